// Round 10
// baseline (206.785 us; speedup 1.0000x reference)
//
#include <hip/hip_runtime.h>
#include <math.h>

typedef _Float16 half8 __attribute__((ext_vector_type(8)));
typedef float f32x4 __attribute__((ext_vector_type(4)));

namespace {
constexpr int NROWS = 16384;        // 16*32*32
constexpr int DDIM  = 256;
constexpr int KCODES = 8192;
constexpr size_t LOSS_OFF = (size_t)16 * 256 * 32 * 32;  // 4194304
constexpr size_t IDX_OFF  = LOSS_OFF + 1;
constexpr float LSCALE = 2048.f;
constexpr float LINV   = 1.f / 2048.f;
// workspace layout (bytes)
constexpr size_t WS_WH   = 0;                    // 4 MB fp16 hi plane, swizzled
constexpr size_t WS_WN   = 4194304;              // 8192 f32 |w|^2
constexpr size_t WS_PV   = WS_WN + 32768;        // [4][16384] f32 best per quarter
constexpr size_t WS_PI   = WS_PV + 262144;       // [4][16384] i32 best idx
constexpr size_t WS_PS2  = WS_PI + 262144;       // [4][16384] f32 2nd-best
constexpr size_t WS_TH   = WS_PS2 + 262144;      // 16384 f32 flag threshold
constexpr size_t WS_IDX  = WS_TH + 65536;        // 16384 i32 preliminary indices
constexpr size_t WS_FLG  = WS_IDX + 65536;       // 16384 i32 flagged? (0/1)
constexpr size_t WS_LIST = WS_FLG + 65536;       // 16384 i32 flagged-row list
constexpr size_t WS_RSV  = WS_LIST + 65536;      // [16384][8] f32 rescore slice vals
constexpr size_t WS_RSI  = WS_RSV + 524288;      // [16384][8] i32 rescore slice idx
constexpr size_t WS_CNT  = WS_RSI + 524288;      // u32 flagged count
constexpr size_t WS_PART = WS_CNT + 256;         // 256 f32 loss partials
constexpr size_t WS_BMAX = WS_PART + 1024;       // [1024][2] f32 per-block maxima
constexpr size_t WS_NEED = WS_BMAX + 8192;       // ~6.3 MB (< 8.7 MB proven in r3)
}

// ============================================================================
// Pre-convert codebook: fp32 -> fp16 hi plane (swizzled); |w|^2 per code;
// per-block maxima via plain stores (r6: same-address atomicMax cost ~130us).
// Block 0 also zeroes the flag counter (ws poisoned only once pre-timing).
// Plane: [tile=code>>7][kc=d>>6][c=code&127][g^(c&7)] x 16B
// ============================================================================
__global__ __launch_bounds__(256)
void vq_prep(const float* __restrict__ w, unsigned char* __restrict__ ws)
{
    __shared__ float rF[4], rS[4];
    if (blockIdx.x == 0 && threadIdx.x == 0) *(unsigned*)(ws + WS_CNT) = 0u;
    const int tau = blockIdx.x * 256 + threadIdx.x;   // 0..262143
    const int gcode = tau >> 5;                       // 0..8191
    const int sub = tau & 31;
    const int kc = sub >> 3, g = sub & 7;
    const float* src = w + (size_t)gcode * 256 + kc * 64 + g * 8;
    float x[8];
    *reinterpret_cast<float4*>(x)     = *reinterpret_cast<const float4*>(src);
    *reinterpret_cast<float4*>(x + 4) = *reinterpret_cast<const float4*>(src + 4);
    half8 hi;
    float sq = 0.f, fq = 0.f;
    #pragma unroll
    for (int j = 0; j < 8; ++j) {
        float v = x[j];
        sq = fmaf(v, v, sq);
        _Float16 h = (_Float16)v;
        hi[j] = h;
        float res = v - (float)h;
        fq = fmaf(res, res, fq);
    }
    const size_t off = (size_t)(gcode >> 7) * 65536 + (size_t)kc * 16384
                     + (size_t)(gcode & 127) * 128 + (size_t)((g ^ (gcode & 7)) << 4);
    *reinterpret_cast<half8*>(ws + WS_WH + off) = hi;
    #pragma unroll
    for (int o = 16; o > 0; o >>= 1) {
        sq += __shfl_down(sq, o, 32);
        fq += __shfl_down(fq, o, 32);
    }
    if (sub == 0) ((float*)(ws + WS_WN))[gcode] = sq;
    float sqc = (sub == 0) ? sq : 0.f;
    float fqc = (sub == 0) ? fq : 0.f;
    #pragma unroll
    for (int o = 32; o > 0; o >>= 1) {
        sqc = fmaxf(sqc, __shfl_xor(sqc, o, 64));
        fqc = fmaxf(fqc, __shfl_xor(fqc, o, 64));
    }
    if ((threadIdx.x & 63) == 0) { rF[threadIdx.x >> 6] = fqc; rS[threadIdx.x >> 6] = sqc; }
    __syncthreads();
    if (threadIdx.x == 0) {
        float* bm = (float*)(ws + WS_BMAX);
        bm[blockIdx.x * 2]     = fmaxf(fmaxf(rF[0], rF[1]), fmaxf(rF[2], rF[3]));
        bm[blockIdx.x * 2 + 1] = fmaxf(fmaxf(rS[0], rS[1]), fmaxf(rS[2], rS[3]));
    }
}

// ============================================================================
// Stage 1: 1-pass zh*wh MFMA GEMM with per-row top-2 tracking.
// Block = 256 thr (4 waves, 2M x 2N), 64 rows x 2048 codes (quarter).
// grid 1024: rg = bid>>2, q = bid&3. Inner per-wave code identical to the
// r6/r9-proven 98us kernel; changes: 3x16KB arena (LDS 51KB -> 3 blocks/CU,
// launch_bounds(256,3) cap=170 >> 104 so no r8-style spill), depth-2
// prefetch (vmcnt 4/0), BMAX max-reduce folded in (saves a launch).
// NO setprio (r7: regressed this lockstep structure 98->111).
// 3-slot safety: write slot (ct+2)%3 at phase ct only races reads at ct-1,
// ordered by the top-of-phase barrier (issue is after the barrier).
// ============================================================================
__global__ __launch_bounds__(256, 3)
void vq_stage1(const float* __restrict__ z, unsigned char* __restrict__ ws)
{
    __shared__ __align__(16) unsigned char A[49152];
    __shared__ float SCR[64][8];   // early: STE[.][0..3], STN[.][4..7]
                                   // late:  MS1[.][0..1], MI1 bits[.][2..3], MS2[.][4..5]
    __shared__ float rF[4], rS[4];

    const int t = threadIdx.x;
    const int lane = t & 63;
    const int wv = t >> 6;          // 0..3
    const int wm = wv >> 1;
    const int wng = wv & 1;
    const int rl = lane & 15, lh = lane >> 4;
    const int bid = blockIdx.x;
    const int rg = bid >> 2;
    const int q  = bid & 3;
    const int r0 = rg * 64;
    const int bb = r0 >> 10;
    const int rem0 = r0 & 1023;
    const float* zbase = z + (size_t)bb * 256 * 1024 + rem0;

    // ---- per-thread partial of global maxima (overlaps staging loads) ----
    const float* bm = (const float*)(ws + WS_BMAX);
    float fmx = 0.f, smx = 0.f;
    #pragma unroll
    for (int i = 0; i < 4; ++i) {
        fmx = fmaxf(fmx, bm[(t + i * 256) * 2]);
        smx = fmaxf(smx, bm[(t + i * 256) * 2 + 1]);
    }

    // ---- stage zh (fp16, swizzled) + per-row residual/norm partials ----
    {
        const int r = t & 63;
        const int ob = t >> 6;
        float e2 = 0.f, n2 = 0.f;
        #pragma unroll
        for (int i = 0; i < 8; ++i) {
            const int o = ob * 8 + i;
            half8 hi;
            #pragma unroll
            for (int j = 0; j < 8; ++j) {
                float v = zbase[(size_t)(o * 8 + j) * 1024 + r];
                _Float16 h = (_Float16)v;
                hi[j] = h;
                float res = v - (float)h;
                e2 = fmaf(res, res, e2);
                n2 = fmaf((float)h, (float)h, n2);
            }
            *reinterpret_cast<half8*>(A + r * 512 + ((o ^ (r & 7)) << 4)) = hi;
        }
        SCR[r][ob] = e2;
        SCR[r][4 + ob] = n2;
    }
    // wave-reduce the maxima partials
    #pragma unroll
    for (int o = 32; o > 0; o >>= 1) {
        fmx = fmaxf(fmx, __shfl_xor(fmx, o, 64));
        smx = fmaxf(smx, __shfl_xor(smx, o, 64));
    }
    if (lane == 0) { rF[wv] = fmx; rS[wv] = smx; }
    __syncthreads();

    // ---- hoist zh fragments to registers: ah[kc][ks][m] ----
    half8 ah[4][2][2];
    #pragma unroll
    for (int kc = 0; kc < 4; ++kc)
        #pragma unroll
        for (int ks = 0; ks < 2; ++ks)
            #pragma unroll
            for (int m = 0; m < 2; ++m) {
                const int r = wm * 32 + m * 16 + rl;
                const int g = kc * 8 + ks * 4 + lh;
                ah[kc][ks][m] = *reinterpret_cast<const half8*>(
                    A + r * 512 + ((g ^ (r & 7)) << 4));
            }
    __syncthreads();    // staging region now free -> W-chunk arena

    // ---- per-row flag threshold (q==0 blocks only; SCR read-only here) ----
    if (t < 64 && q == 0) {
        float e2 = SCR[t][0] + SCR[t][1] + SCR[t][2] + SCR[t][3];
        float n2 = SCR[t][4] + SCR[t][5] + SCR[t][6] + SCR[t][7];
        float Fm = sqrtf(fmaxf(fmaxf(rF[0], rF[1]), fmaxf(rF[2], rF[3])));
        float Wm = sqrtf(fmaxf(fmaxf(rS[0], rS[1]), fmaxf(rS[2], rS[3])));
        ((float*)(ws + WS_TH))[r0 + t] = 0.75f * (sqrtf(n2) * Fm + sqrtf(e2) * Wm) + 0.03f;
    }

    const unsigned char* wplane = ws + WS_WH;
    // chunk ct in 0..63: code tile = q*16 + (ct>>2), kc = ct&3, slot = ct%3
    auto issue = [&](int ct) {
        const int slot = ct % 3;
        const unsigned char* src = wplane + (size_t)(q * 16 + (ct >> 2)) * 65536
                                 + (size_t)(ct & 3) * 16384;
        unsigned char* dst = A + slot * 16384;
        #pragma unroll
        for (int i = 0; i < 4; ++i) {
            const int gran = wv * 256 + i * 64 + lane;
            __builtin_amdgcn_global_load_lds(
                (const __attribute__((address_space(1))) unsigned int*)(src + (size_t)gran * 16),
                (__attribute__((address_space(3))) unsigned int*)(dst + (size_t)gran * 16), 16, 0, 0);
        }
    };
    issue(0); issue(1);   // depth-2: 8 loads outstanding

    float s1v[8], s2v[8];
    int   i1v[8];
    #pragma unroll
    for (int s = 0; s < 8; ++s) { s1v[s] = INFINITY; s2v[s] = INFINITY; i1v[s] = 0; }
    const float* wnp = (const float*)(ws + WS_WN);

    f32x4 acc[2][4];
    for (int t4 = 0; t4 < 16; ++t4) {
        #pragma unroll
        for (int kc = 0; kc < 4; ++kc) {
            const int ct = t4 * 4 + kc;     // 0..63
            if (t4 == 15 && kc == 3) asm volatile("s_waitcnt vmcnt(0)" ::: "memory");
            else                     asm volatile("s_waitcnt vmcnt(4)" ::: "memory");
            __builtin_amdgcn_s_barrier();
            asm volatile("" ::: "memory");
            if (ct + 2 < 64) issue(ct + 2);

            if (kc == 0) {
                #pragma unroll
                for (int m = 0; m < 2; ++m)
                    #pragma unroll
                    for (int n = 0; n < 4; ++n) acc[m][n] = (f32x4)0.f;
            }
            const unsigned char* wb = A + (ct % 3) * 16384;
            #pragma unroll
            for (int ks = 0; ks < 2; ++ks) {
                half8 bf[4];
                #pragma unroll
                for (int n = 0; n < 4; ++n) {
                    const int cc = wng * 64 + n * 16 + rl;
                    const int gg = ks * 4 + lh;
                    bf[n] = *reinterpret_cast<const half8*>(
                        wb + cc * 128 + ((gg ^ (cc & 7)) << 4));
                }
                #pragma unroll
                for (int m = 0; m < 2; ++m)
                    #pragma unroll
                    for (int n = 0; n < 4; ++n)
                        acc[m][n] = __builtin_amdgcn_mfma_f32_16x16x32_f16(
                            ah[kc][ks][m], bf[n], acc[m][n], 0, 0, 0);
            }
            if (kc == 3) {
                // tile epilogue: s = |w|^2 - 2*dot ; top-2 update (codes ascending)
                const int codebase = q * 2048 + t4 * 128 + wng * 64;
                #pragma unroll
                for (int n = 0; n < 4; ++n) {
                    const int code = codebase + n * 16 + rl;
                    const float wnv = wnp[code];
                    #pragma unroll
                    for (int m = 0; m < 2; ++m)
                        #pragma unroll
                        for (int rr = 0; rr < 4; ++rr) {
                            const int sl = m * 4 + rr;
                            float s = fmaf(-2.f, acc[m][n][rr], wnv);
                            bool lt = s < s1v[sl];
                            s2v[sl] = fminf(s2v[sl], fmaxf(s, s1v[sl]));
                            i1v[sl] = lt ? code : i1v[sl];
                            s1v[sl] = fminf(s1v[sl], s);
                        }
                }
            }
        }
    }

    // ---- cross-lane top-2 merge (16 lanes sharing a row) -> SCR (reused) ----
    #pragma unroll
    for (int sl = 0; sl < 8; ++sl) {
        float v1 = s1v[sl], v2 = s2v[sl];
        int ii = i1v[sl];
        #pragma unroll
        for (int o = 8; o > 0; o >>= 1) {
            float ov1 = __shfl_xor(v1, o, 16);
            float ov2 = __shfl_xor(v2, o, 16);
            int   oi  = __shfl_xor(ii, o, 16);
            float ns2 = fminf(fmaxf(v1, ov1), fminf(v2, ov2));
            bool tk = (ov1 < v1) || (ov1 == v1 && oi < ii);
            v1 = tk ? ov1 : v1;
            ii = tk ? oi : ii;
            v2 = ns2;
        }
        if (rl == 0) {
            const int row = wm * 32 + (sl >> 2) * 16 + lh * 4 + (sl & 3);
            SCR[row][wng] = v1;
            reinterpret_cast<int*>(&SCR[row][2])[wng] = ii;
            SCR[row][4 + wng] = v2;
        }
    }
    __syncthreads();
    if (t < 64) {
        float v0 = SCR[t][0], v1 = SCR[t][1];
        int   i0 = reinterpret_cast<int*>(&SCR[t][2])[0];
        int   i1b = reinterpret_cast<int*>(&SCR[t][2])[1];
        float s20 = SCR[t][4], s21 = SCR[t][5];
        bool tk = (v1 < v0) || (v1 == v0 && i1b < i0);
        float bs1 = tk ? v1 : v0;
        int bi = tk ? i1b : i0;
        float bs2 = fminf(fmaxf(v0, v1), fminf(s20, s21));
        const int grow = r0 + t;
        ((float*)(ws + WS_PV))[q * 16384 + grow] = bs1;
        ((int*)(ws + WS_PI))[q * 16384 + grow] = bi;
        ((float*)(ws + WS_PS2))[q * 16384 + grow] = bs2;
    }
}

// ============================================================================
// Merge 4 quarters -> preliminary idx; flag rows (gap < TH); write flag array
// + compact list. Ascending-quarter fold preserves the first-min tie rule.
// (4-quarter fold correctness-proven in round 8's passing run.)
// ============================================================================
__global__ __launch_bounds__(256)
void vq_flagmerge(unsigned char* __restrict__ ws)
{
    const int row = blockIdx.x * 256 + threadIdx.x;
    const float* PV  = (const float*)(ws + WS_PV);
    const int*   PI  = (const int*)(ws + WS_PI);
    const float* PS2 = (const float*)(ws + WS_PS2);
    float b1 = PV[row];
    int   bi = PI[row];
    float b2 = PS2[row];
    #pragma unroll
    for (int qd = 1; qd < 4; ++qd) {
        float v1 = PV[qd * 16384 + row];
        float v2 = PS2[qd * 16384 + row];
        int   ii = PI[qd * 16384 + row];
        float nb2 = fminf(fmaxf(b1, v1), fminf(b2, v2));
        if (v1 < b1) { b1 = v1; bi = ii; }
        b2 = nb2;
    }
    ((int*)(ws + WS_IDX))[row] = bi;
    float th = ((const float*)(ws + WS_TH))[row];
    int fl = (b2 - b1 < th) ? 1 : 0;
    ((int*)(ws + WS_FLG))[row] = fl;
    if (fl) {
        unsigned p = atomicAdd((unsigned*)(ws + WS_CNT), 1u);
        ((int*)(ws + WS_LIST))[p] = row;
    }
}

// ============================================================================
// Exact-class 3-pass MFMA rescore of flagged rows, SLICED over codes.
// Item = (group of 64 flagged rows, slice of 1024 codes).
// dot = zh*wh + (zl*wh + zh*wl)/2048. Partials keyed by ROW -> deterministic.
// ============================================================================
__global__ __launch_bounds__(256, 1)
void vq_rescore3(const float* __restrict__ z, const float* __restrict__ w,
                 unsigned char* __restrict__ ws)
{
    // LDS: [0,32K) zh | [32K,64K) zl | [64K,128K) arena 2 slots x (wh16K+wl16K) | merge
    __shared__ __align__(16) unsigned char L[132352];
    float* MS1 = (float*)(L + 131072);           // [64][2]
    int*   MI1 = (int*)(L + 131072 + 512);       // [64][2]
    int*   rowsS = (int*)(L + 131072 + 1024);    // [64]

    const int t = threadIdx.x;
    const int lane = t & 63;
    const int wv = t >> 6;
    const int wm = wv >> 1, wng = wv & 1;
    const int rl = lane & 15, lh = lane >> 4;
    const unsigned cnt = *(const unsigned*)(ws + WS_CNT);
    if (cnt == 0) return;
    const unsigned ngroups = (cnt + 63u) >> 6;
    const unsigned items = ngroups * 8u;
    const int* list = (const int*)(ws + WS_LIST);
    const float* wnp = (const float*)(ws + WS_WN);
    float* RSV = (float*)(ws + WS_RSV);
    int*   RSI = (int*)(ws + WS_RSI);

    // stage one W chunk (128 codes x 64 d, fp32 -> hi/lo fp16) into arena slot
    auto stageW = [&](int cb, int kc, int slot) {
        unsigned char* whb = L + 65536 + slot * 32768;
        unsigned char* wlb = whb + 16384;
        #pragma unroll
        for (int i = 0; i < 4; ++i) {
            int task = i * 256 + t;
            int c = task >> 3, go = task & 7;
            const float* wsrc = w + (size_t)(cb + c) * 256 + kc * 64 + go * 8;
            float x[8];
            *reinterpret_cast<float4*>(x)     = *reinterpret_cast<const float4*>(wsrc);
            *reinterpret_cast<float4*>(x + 4) = *reinterpret_cast<const float4*>(wsrc + 4);
            half8 hi, lo;
            #pragma unroll
            for (int j = 0; j < 8; ++j) {
                float v = x[j];
                _Float16 h = (_Float16)v;
                hi[j] = h;
                lo[j] = (_Float16)((v - (float)h) * LSCALE);
            }
            const int woff = c * 128 + ((go ^ (c & 7)) << 4);
            *reinterpret_cast<half8*>(whb + woff) = hi;
            *reinterpret_cast<half8*>(wlb + woff) = lo;
        }
    };

    for (unsigned item = blockIdx.x; item < items; item += gridDim.x) {
        const unsigned g = item >> 3;
        const int s = (int)(item & 7u);

        if (t < 64) {
            unsigned li = g * 64u + (unsigned)t;
            rowsS[t] = list[li < cnt ? li : cnt - 1u];
        }
        __syncthreads();

        // ---- stage gathered z rows -> zh/zl (fp16, swizzled) ----
        {
            const int r = t & 63, qq = t >> 6;
            const int row = rowsS[r];
            const float* zb = z + ((size_t)(row >> 10) * 256 + qq * 64) * 1024 + (row & 1023);
            #pragma unroll
            for (int o = 0; o < 8; ++o) {
                half8 hi, lo;
                #pragma unroll
                for (int j = 0; j < 8; ++j) {
                    float v = zb[(size_t)(o * 8 + j) * 1024];
                    _Float16 h = (_Float16)v;
                    hi[j] = h;
                    lo[j] = (_Float16)((v - (float)h) * LSCALE);
                }
                const int go = qq * 8 + o;
                const int zoff = r * 512 + ((go ^ (r & 7)) << 4);
                *reinterpret_cast<half8*>(L + zoff) = hi;
                *reinterpret_cast<half8*>(L + 32768 + zoff) = lo;
            }
        }
        __syncthreads();

        // ---- hoist zh fragments ----
        half8 ah[4][2][2];
        #pragma unroll
        for (int kc = 0; kc < 4; ++kc)
            #pragma unroll
            for (int ks = 0; ks < 2; ++ks)
                #pragma unroll
                for (int m = 0; m < 2; ++m) {
                    const int r = wm * 32 + m * 16 + rl;
                    const int gg = kc * 8 + ks * 4 + lh;
                    ah[kc][ks][m] = *reinterpret_cast<const half8*>(
                        L + r * 512 + ((gg ^ (r & 7)) << 4));
                }

        float bv[8]; int bix[8];
        #pragma unroll
        for (int sl = 0; sl < 8; ++sl) { bv[sl] = INFINITY; bix[sl] = 0; }

        const int cbase0 = s * 1024;
        stageW(cbase0, 0, 0);
        __syncthreads();

        f32x4 accM[2][4], accC[2][4];
        for (int tile = 0; tile < 8; ++tile) {
            const int cb = cbase0 + tile * 128;
            #pragma unroll
            for (int kc = 0; kc < 4; ++kc) {
                // prefetch next chunk into the other slot (overlaps with MFMA)
                if (kc < 3)           stageW(cb, kc + 1, (kc + 1) & 1);
                else if (tile < 7)    stageW(cbase0 + (tile + 1) * 128, 0, 0);

                if (kc == 0) {
                    #pragma unroll
                    for (int m = 0; m < 2; ++m)
                        #pragma unroll
                        for (int n = 0; n < 4; ++n) {
                            accM[m][n] = (f32x4)0.f;
                            accC[m][n] = (f32x4)0.f;
                        }
                }
                const unsigned char* whb = L + 65536 + (kc & 1) * 32768;
                const unsigned char* wlb = whb + 16384;
                #pragma unroll
                for (int ks = 0; ks < 2; ++ks) {
                    half8 bfh[4], bfl[4];
                    #pragma unroll
                    for (int n = 0; n < 4; ++n) {
                        const int cc = wng * 64 + n * 16 + rl;
                        const int gg = ks * 4 + lh;
                        const int woff = cc * 128 + ((gg ^ (cc & 7)) << 4);
                        bfh[n] = *reinterpret_cast<const half8*>(whb + woff);
                        bfl[n] = *reinterpret_cast<const half8*>(wlb + woff);
                    }
                    #pragma unroll
                    for (int m = 0; m < 2; ++m)
                        #pragma unroll
                        for (int n = 0; n < 4; ++n)
                            accM[m][n] = __builtin_amdgcn_mfma_f32_16x16x32_f16(
                                ah[kc][ks][m], bfh[n], accM[m][n], 0, 0, 0);
                    #pragma unroll
                    for (int m = 0; m < 2; ++m) {
                        const int r = wm * 32 + m * 16 + rl;
                        const int gg = kc * 8 + ks * 4 + lh;
                        half8 al = *reinterpret_cast<const half8*>(
                            L + 32768 + r * 512 + ((gg ^ (r & 7)) << 4));
                        #pragma unroll
                        for (int n = 0; n < 4; ++n)
                            accC[m][n] = __builtin_amdgcn_mfma_f32_16x16x32_f16(
                                al, bfh[n], accC[m][n], 0, 0, 0);
                    }
                    #pragma unroll
                    for (int m = 0; m < 2; ++m)
                        #pragma unroll
                        for (int n = 0; n < 4; ++n)
                            accC[m][n] = __builtin_amdgcn_mfma_f32_16x16x32_f16(
                                ah[kc][ks][m], bfl[n], accC[m][n], 0, 0, 0);
                }

                if (kc == 3) {
                    // tile epilogue: top-1 (codes ascending, strict <)
                    #pragma unroll
                    for (int n = 0; n < 4; ++n) {
                        const int code = cb + wng * 64 + n * 16 + rl;
                        const float wnv = wnp[code];
                        #pragma unroll
                        for (int m = 0; m < 2; ++m)
                            #pragma unroll
                            for (int rr = 0; rr < 4; ++rr) {
                                const int sl = m * 4 + rr;
                                float dot = accM[m][n][rr] + accC[m][n][rr] * LINV;
                                float sc = fmaf(-2.f, dot, wnv);
                                if (sc < bv[sl]) { bv[sl] = sc; bix[sl] = code; }
                            }
                    }
                }
                __syncthreads();   // chunk boundary: staged data ready / arena reusable
            }
        }

        // ---- cross-lane top-1 reduce + write row-keyed partials ----
        #pragma unroll
        for (int sl = 0; sl < 8; ++sl) {
            float v = bv[sl]; int ix = bix[sl];
            #pragma unroll
            for (int o = 8; o > 0; o >>= 1) {
                float ov = __shfl_xor(v, o, 16);
                int   oi = __shfl_xor(ix, o, 16);
                if (ov < v || (ov == v && oi < ix)) { v = ov; ix = oi; }
            }
            if (rl == 0) {
                const int row = wm * 32 + (sl >> 2) * 16 + lh * 4 + (sl & 3);
                MS1[row * 2 + wng] = v; MI1[row * 2 + wng] = ix;
            }
        }
        __syncthreads();
        if (t < 64) {
            float v0 = MS1[t * 2 + 0], v1 = MS1[t * 2 + 1];
            int   i0 = MI1[t * 2 + 0], i1 = MI1[t * 2 + 1];
            bool tk = (v1 < v0) || (v1 == v0 && i1 < i0);
            float v = tk ? v1 : v0;
            int ix = tk ? i1 : i0;
            if (g * 64u + (unsigned)t < cnt) {
                const int row = rowsS[t];
                RSV[(size_t)row * 8 + s] = v;
                RSI[(size_t)row * 8 + s] = ix;
            }
        }
        __syncthreads();   // before next item's staging
    }
}

// ============================================================================
// Final indices (inline 8-slice merge for flagged rows), gather z_q,
// direct loss partial sum. (rescmerge folded in; keyed by row -> determ.)
// ============================================================================
__global__ __launch_bounds__(256)
void vq_gather(const float* __restrict__ z, const float* __restrict__ w,
               const unsigned char* __restrict__ ws, float* __restrict__ out,
               float* __restrict__ part)
{
    __shared__ int sidx[64];
    __shared__ float s4[4];
    const int t = threadIdx.x;
    const int n0 = blockIdx.x * 64;
    const int bb = n0 >> 10, rem0 = n0 & 1023;
    if (t < 64) {
        const int row = n0 + t;
        int ix = ((const int*)(ws + WS_IDX))[row];
        if (((const int*)(ws + WS_FLG))[row]) {
            const float* RSV = (const float*)(ws + WS_RSV);
            const int*   RSI = (const int*)(ws + WS_RSI);
            float bvv = RSV[(size_t)row * 8];
            int bi = RSI[(size_t)row * 8];
            #pragma unroll
            for (int s = 1; s < 8; ++s) {
                float v = RSV[(size_t)row * 8 + s];
                int ix2 = RSI[(size_t)row * 8 + s];
                if (v < bvv || (v == bvv && ix2 < bi)) { bvv = v; bi = ix2; }
            }
            ix = bi;
        }
        sidx[t] = ix;
        out[IDX_OFF + row] = (float)ix;
    }
    __syncthreads();
    const int r = t & 63, dq = t >> 6;
    const int idx = sidx[r];
    const float4* wrow = reinterpret_cast<const float4*>(w + (size_t)idx * 256 + dq * 64);
    const float* zb = z   + ((size_t)bb * 256 + dq * 64) * 1024 + rem0 + r;
    float*       ob = out + ((size_t)bb * 256 + dq * 64) * 1024 + rem0 + r;
    float acc = 0.f;
    #pragma unroll
    for (int d4 = 0; d4 < 16; ++d4) {
        float4 v = wrow[d4];
        float z0 = zb[(size_t)(d4 * 4 + 0) * 1024];
        float z1 = zb[(size_t)(d4 * 4 + 1) * 1024];
        float z2 = zb[(size_t)(d4 * 4 + 2) * 1024];
        float z3 = zb[(size_t)(d4 * 4 + 3) * 1024];
        ob[(size_t)(d4 * 4 + 0) * 1024] = v.x;
        ob[(size_t)(d4 * 4 + 1) * 1024] = v.y;
        ob[(size_t)(d4 * 4 + 2) * 1024] = v.z;
        ob[(size_t)(d4 * 4 + 3) * 1024] = v.w;
        float d0 = z0 - v.x, d1 = z1 - v.y, d2 = z2 - v.z, d3 = z3 - v.w;
        acc = fmaf(d0, d0, acc); acc = fmaf(d1, d1, acc);
        acc = fmaf(d2, d2, acc); acc = fmaf(d3, d3, acc);
    }
    #pragma unroll
    for (int o = 32; o > 0; o >>= 1) acc += __shfl_down(acc, o, 64);
    if ((t & 63) == 0) s4[t >> 6] = acc;
    __syncthreads();
    if (t == 0) part[blockIdx.x] = s4[0] + s4[1] + s4[2] + s4[3];
}

__global__ void vq_finish_kernel(const float* __restrict__ part, float* __restrict__ out)
{
    __shared__ float s4[4];
    int t = threadIdx.x;
    float v = part[t];
    #pragma unroll
    for (int off = 32; off > 0; off >>= 1) v += __shfl_down(v, off, 64);
    if ((t & 63) == 0) s4[t >> 6] = v;
    __syncthreads();
    if (t == 0) {
        float tot = s4[0] + s4[1] + s4[2] + s4[3];
        out[LOSS_OFF] = 0.25f * tot / ((float)NROWS * (float)DDIM);
    }
}

// ============================================================================
// Fallback (proven round-2 fp32 path) used only when ws_size is too small.
// ============================================================================
namespace fb {
constexpr int BM = 64, BN = 64, NCHUNK = KCODES / BN, BSTR = 257;
}
__global__ __launch_bounds__(256, 1)
void vq_main_fp32(const float* __restrict__ z, const float* __restrict__ w,
                  float* __restrict__ out, float* __restrict__ part)
{
    using namespace fb;
    __shared__ float At[DDIM][BM];
    __shared__ float Bt[BN][BSTR];
    __shared__ float zn_s[BM];
    __shared__ float wn4[BM][5];
    __shared__ float cmin[BM][17];
    __shared__ int   cidx[BM][17];
    __shared__ int   fidx_s[BM];

    const int t = threadIdx.x;
    const int n0 = blockIdx.x * BM;
    const int bb = n0 >> 10;
    const int rem0 = n0 & 1023;
    const float* zbase = z + (size_t)bb * DDIM * 1024 + rem0;

    #pragma unroll
    for (int it = 0; it < 16; ++it) {
        int tau = t + it * 256;
        int d = tau >> 4;
        int r4 = (tau & 15) << 2;
        float4 v = *reinterpret_cast<const float4*>(zbase + (size_t)d * 1024 + r4);
        *reinterpret_cast<float4*>(&At[d][r4]) = v;
    }
    __syncthreads();
    if (t < BM) {
        float s = 0.f;
        #pragma unroll 8
        for (int d = 0; d < DDIM; ++d) { float v = At[d][t]; s = fmaf(v, v, s); }
        zn_s[t] = s;
    }
    const int ty = t >> 4, tx = t & 15;
    float rmin[4]; int ridx[4];
    #pragma unroll
    for (int i = 0; i < 4; ++i) { rmin[i] = INFINITY; ridx[i] = 0; }

    for (int nc = 0; nc < NCHUNK; ++nc) {
        const float* wb = w + (size_t)nc * BN * DDIM;
        #pragma unroll
        for (int it = 0; it < 16; ++it) {
            int tau = t + it * 256;
            int k = tau >> 6;
            int d4 = (tau & 63) << 2;
            float4 v = *reinterpret_cast<const float4*>(wb + (size_t)k * DDIM + d4);
            Bt[k][d4 + 0] = v.x; Bt[k][d4 + 1] = v.y;
            Bt[k][d4 + 2] = v.z; Bt[k][d4 + 3] = v.w;
        }
        __syncthreads();
        {
            int k = t & 63, q = t >> 6;
            float s = 0.f;
            const int d0 = q * 64;
            #pragma unroll 8
            for (int d = 0; d < 64; ++d) { float v = Bt[k][d0 + d]; s = fmaf(v, v, s); }
            wn4[k][q] = s;
        }
        float acc[4][4];
        #pragma unroll
        for (int i = 0; i < 4; ++i)
            #pragma unroll
            for (int j = 0; j < 4; ++j) acc[i][j] = 0.f;
        #pragma unroll 8
        for (int kk = 0; kk < DDIM; ++kk) {
            float a[4], bvv[4];
            *reinterpret_cast<float4*>(a) =
                *reinterpret_cast<const float4*>(&At[kk][ty << 2]);
            #pragma unroll
            for (int j = 0; j < 4; ++j) bvv[j] = Bt[(tx << 2) + j][kk];
            #pragma unroll
            for (int i = 0; i < 4; ++i)
                #pragma unroll
                for (int j = 0; j < 4; ++j) acc[i][j] = fmaf(a[i], bvv[j], acc[i][j]);
        }
        __syncthreads();
        #pragma unroll
        for (int j = 0; j < 4; ++j) {
            int c = (tx << 2) + j;
            float wn = wn4[c][0] + wn4[c][1] + wn4[c][2] + wn4[c][3];
            int gidx = nc * BN + c;
            #pragma unroll
            for (int i = 0; i < 4; ++i) {
                float s = fmaf(-2.f, acc[i][j], wn);
                if (s < rmin[i]) { rmin[i] = s; ridx[i] = gidx; }
            }
        }
    }
    #pragma unroll
    for (int i = 0; i < 4; ++i) {
        cmin[(ty << 2) + i][tx] = rmin[i];
        cidx[(ty << 2) + i][tx] = ridx[i];
    }
    __syncthreads();
    float dist = 0.f;
    if (t < BM) {
        float bestv = cmin[t][0]; int besti = cidx[t][0];
        #pragma unroll
        for (int x = 1; x < 16; ++x) {
            float v = cmin[t][x]; int ix = cidx[t][x];
            if (v < bestv || (v == bestv && ix < besti)) { bestv = v; besti = ix; }
        }
        fidx_s[t] = besti;
        out[IDX_OFF + n0 + t] = (float)besti;
        dist = zn_s[t] + bestv;
    }
    if (t < 64) {
        #pragma unroll
        for (int off = 32; off > 0; off >>= 1) dist += __shfl_down(dist, off, 64);
        if (t == 0) part[blockIdx.x] = dist;
    }
    __syncthreads();
    {
        int r = t & 63, dq = t >> 6;
        int idx = fidx_s[r];
        const float4* wrow = reinterpret_cast<const float4*>(w + (size_t)idx * DDIM + dq * 64);
        float* obase = out + ((size_t)bb * DDIM + dq * 64) * 1024 + rem0 + r;
        #pragma unroll
        for (int d4 = 0; d4 < 16; ++d4) {
            float4 v = wrow[d4];
            obase[(size_t)(d4 * 4 + 0) * 1024] = v.x;
            obase[(size_t)(d4 * 4 + 1) * 1024] = v.y;
            obase[(size_t)(d4 * 4 + 2) * 1024] = v.z;
            obase[(size_t)(d4 * 4 + 3) * 1024] = v.w;
        }
    }
}

extern "C" void kernel_launch(void* const* d_in, const int* in_sizes, int n_in,
                              void* d_out, int out_size, void* d_ws, size_t ws_size,
                              hipStream_t stream) {
    const float* z = (const float*)d_in[0];
    const float* w = (const float*)d_in[1];
    float* out = (float*)d_out;
    if (ws_size >= WS_NEED) {
        unsigned char* ws = (unsigned char*)d_ws;
        float* part = (float*)(ws + WS_PART);
        vq_prep<<<1024, 256, 0, stream>>>(w, ws);
        vq_stage1<<<1024, 256, 0, stream>>>(z, ws);
        vq_flagmerge<<<64, 256, 0, stream>>>(ws);
        vq_rescore3<<<2048, 256, 0, stream>>>(z, w, ws);
        vq_gather<<<256, 256, 0, stream>>>(z, w, ws, out, part);
        vq_finish_kernel<<<1, 256, 0, stream>>>(part, out);
    } else {
        float* part = (float*)d_ws;
        vq_main_fp32<<<NROWS / fb::BM, 256, 0, stream>>>(z, w, out, part);
        vq_finish_kernel<<<1, 256, 0, stream>>>(part, out);
    }
}

// Round 11
// 166.203 us; speedup vs baseline: 1.2442x; 1.2442x over previous
//
#include <hip/hip_runtime.h>
#include <math.h>

typedef _Float16 half8 __attribute__((ext_vector_type(8)));
typedef float f32x4 __attribute__((ext_vector_type(4)));

namespace {
constexpr int NROWS = 16384;        // 16*32*32
constexpr int DDIM  = 256;
constexpr int KCODES = 8192;
constexpr size_t LOSS_OFF = (size_t)16 * 256 * 32 * 32;  // 4194304
constexpr size_t IDX_OFF  = LOSS_OFF + 1;
constexpr float LSCALE = 2048.f;
constexpr float LINV   = 1.f / 2048.f;
// workspace layout (bytes)
constexpr size_t WS_WH   = 0;                    // 4 MB fp16 hi plane, swizzled
constexpr size_t WS_WN   = 4194304;              // 8192 f32 |w|^2
constexpr size_t WS_PV   = WS_WN + 32768;        // [2][16384] f32 best value per half
constexpr size_t WS_PI   = WS_PV + 131072;       // [2][16384] i32 best idx per half
constexpr size_t WS_PS2  = WS_PI + 131072;       // [2][16384] f32 2nd-best per half
constexpr size_t WS_TH   = WS_PS2 + 131072;      // 16384 f32 per-row flag threshold
constexpr size_t WS_IDX  = WS_TH + 65536;        // 16384 i32 preliminary indices
constexpr size_t WS_FLG  = WS_IDX + 65536;       // 16384 i32 flagged? (0/1)
constexpr size_t WS_LIST = WS_FLG + 65536;       // 16384 i32 flagged-row list
constexpr size_t WS_RSV  = WS_LIST + 65536;      // [16384][8] f32 rescore slice vals
constexpr size_t WS_RSI  = WS_RSV + 524288;      // [16384][8] i32 rescore slice idx
constexpr size_t WS_CNT  = WS_RSI + 524288;      // u32 flagged count
constexpr size_t WS_FMAX = WS_CNT + 4;           // f32 max residual^2 (plain store)
constexpr size_t WS_WMAX = WS_CNT + 8;           // f32 max |w|^2 (plain store)
constexpr size_t WS_PART = WS_CNT + 256;         // 256 f32 loss partials
constexpr size_t WS_BMAX = WS_PART + 1024;       // [1024][2] f32 per-block maxima
constexpr size_t WS_NEED = WS_BMAX + 8192;       // ~5.7 MB
}

// ============================================================================
// Pre-convert codebook: fp32 -> fp16 hi plane (swizzled); |w|^2 per code;
// per-block maxima via plain stores (r6: same-address atomicMax cost ~130us).
// Plane: [tile=code>>7][kc=d>>6][c=code&127][g^(c&7)] x 16B
// ============================================================================
__global__ __launch_bounds__(256)
void vq_prep(const float* __restrict__ w, unsigned char* __restrict__ ws)
{
    __shared__ float rF[4], rS[4];
    const int tau = blockIdx.x * 256 + threadIdx.x;   // 0..262143
    const int gcode = tau >> 5;                       // 0..8191
    const int sub = tau & 31;
    const int kc = sub >> 3, g = sub & 7;
    const float* src = w + (size_t)gcode * 256 + kc * 64 + g * 8;
    float x[8];
    *reinterpret_cast<float4*>(x)     = *reinterpret_cast<const float4*>(src);
    *reinterpret_cast<float4*>(x + 4) = *reinterpret_cast<const float4*>(src + 4);
    half8 hi;
    float sq = 0.f, fq = 0.f;
    #pragma unroll
    for (int j = 0; j < 8; ++j) {
        float v = x[j];
        sq = fmaf(v, v, sq);
        _Float16 h = (_Float16)v;
        hi[j] = h;
        float res = v - (float)h;
        fq = fmaf(res, res, fq);
    }
    const size_t off = (size_t)(gcode >> 7) * 65536 + (size_t)kc * 16384
                     + (size_t)(gcode & 127) * 128 + (size_t)((g ^ (gcode & 7)) << 4);
    *reinterpret_cast<half8*>(ws + WS_WH + off) = hi;
    #pragma unroll
    for (int o = 16; o > 0; o >>= 1) {
        sq += __shfl_down(sq, o, 32);
        fq += __shfl_down(fq, o, 32);
    }
    if (sub == 0) ((float*)(ws + WS_WN))[gcode] = sq;
    float sqc = (sub == 0) ? sq : 0.f;
    float fqc = (sub == 0) ? fq : 0.f;
    #pragma unroll
    for (int o = 32; o > 0; o >>= 1) {
        sqc = fmaxf(sqc, __shfl_xor(sqc, o, 64));
        fqc = fmaxf(fqc, __shfl_xor(fqc, o, 64));
    }
    if ((threadIdx.x & 63) == 0) { rF[threadIdx.x >> 6] = fqc; rS[threadIdx.x >> 6] = sqc; }
    __syncthreads();
    if (threadIdx.x == 0) {
        float* bm = (float*)(ws + WS_BMAX);
        bm[blockIdx.x * 2]     = fmaxf(fmaxf(rF[0], rF[1]), fmaxf(rF[2], rF[3]));
        bm[blockIdx.x * 2 + 1] = fmaxf(fmaxf(rS[0], rS[1]), fmaxf(rS[2], rS[3]));
    }
}

// ============================================================================
// Reduce 1024 per-block maxima -> FMAX/WMAX; zero flag counter.
// ============================================================================
__global__ __launch_bounds__(256)
void vq_maxreduce(unsigned char* __restrict__ ws)
{
    __shared__ float rF[4], rS[4];
    const int t = threadIdx.x;
    const float* bm = (const float*)(ws + WS_BMAX);
    float f = 0.f, s = 0.f;
    #pragma unroll
    for (int i = 0; i < 4; ++i) {
        f = fmaxf(f, bm[(t + i * 256) * 2]);
        s = fmaxf(s, bm[(t + i * 256) * 2 + 1]);
    }
    #pragma unroll
    for (int o = 32; o > 0; o >>= 1) {
        f = fmaxf(f, __shfl_xor(f, o, 64));
        s = fmaxf(s, __shfl_xor(s, o, 64));
    }
    if ((t & 63) == 0) { rF[t >> 6] = f; rS[t >> 6] = s; }
    __syncthreads();
    if (t == 0) {
        *(float*)(ws + WS_FMAX) = fmaxf(fmaxf(rF[0], rF[1]), fmaxf(rF[2], rF[3]));
        *(float*)(ws + WS_WMAX) = fmaxf(fmaxf(rS[0], rS[1]), fmaxf(rS[2], rS[3]));
        *(unsigned*)(ws + WS_CNT) = 0u;
    }
}

// ============================================================================
// Stage 1 -- r9-proven config, byte-identical (98 us, MfmaUtil 30, VGPR 104,
// WRITE ~0.45MB). Do NOT touch: launch_bounds(256,2) [r8/r10: any tighter
// occupancy bound spills ah[] -> scratch, WRITE_SIZE jumps to 13-64MB];
// no setprio [r7: lockstep barrier structure, regressed 98->111].
// Block = 256 thr (4 waves, 2M x 2N), 64 rows x 4096 codes (half).
// grid 512: rg = bid>>1, half = bid&1. 4x16KB arena, vmcnt 8/4/0.
// ============================================================================
__global__ __launch_bounds__(256, 2)
void vq_stage1(const float* __restrict__ z, unsigned char* __restrict__ ws)
{
    __shared__ __align__(16) unsigned char A[65536];
    __shared__ float MS1[64][2];
    __shared__ int   MI1[64][2];
    __shared__ float MS2[64][2];
    __shared__ float STE[64][4];
    __shared__ float STN[64][4];

    const int t = threadIdx.x;
    const int lane = t & 63;
    const int wv = t >> 6;          // 0..3
    const int wm = wv >> 1;         // row group of 32
    const int wng = wv & 1;         // code group of 64
    const int rl = lane & 15, lh = lane >> 4;
    const int bid = blockIdx.x;
    const int rg = bid >> 1;
    const int half = bid & 1;
    const int r0 = rg * 64;
    const int bb = r0 >> 10;
    const int rem0 = r0 & 1023;
    const float* zbase = z + (size_t)bb * 256 * 1024 + rem0;

    // ---- stage zh (fp16, swizzled) + per-row residual/norm partials ----
    {
        const int r = t & 63;
        const int ob = t >> 6;               // 0..3 -> d range [ob*64, ob*64+64)
        float e2 = 0.f, n2 = 0.f;
        #pragma unroll
        for (int i = 0; i < 8; ++i) {
            const int o = ob * 8 + i;        // k-octet
            half8 hi;
            #pragma unroll
            for (int j = 0; j < 8; ++j) {
                float v = zbase[(size_t)(o * 8 + j) * 1024 + r];
                _Float16 h = (_Float16)v;
                hi[j] = h;
                float res = v - (float)h;
                e2 = fmaf(res, res, e2);
                n2 = fmaf((float)h, (float)h, n2);
            }
            *reinterpret_cast<half8*>(A + r * 512 + ((o ^ (r & 7)) << 4)) = hi;
        }
        STE[r][ob] = e2;
        STN[r][ob] = n2;
    }
    __syncthreads();

    // ---- per-row flag threshold (written once, by half==0 blocks) ----
    if (t < 64 && half == 0) {
        float e2 = STE[t][0] + STE[t][1] + STE[t][2] + STE[t][3];
        float n2 = STN[t][0] + STN[t][1] + STN[t][2] + STN[t][3];
        float Fm = sqrtf(*(const float*)(ws + WS_FMAX));
        float Wm = sqrtf(*(const float*)(ws + WS_WMAX));
        ((float*)(ws + WS_TH))[r0 + t] = 0.75f * (sqrtf(n2) * Fm + sqrtf(e2) * Wm) + 0.03f;
    }

    // ---- hoist zh fragments to registers: ah[kc][ks][m] ----
    half8 ah[4][2][2];
    #pragma unroll
    for (int kc = 0; kc < 4; ++kc)
        #pragma unroll
        for (int ks = 0; ks < 2; ++ks)
            #pragma unroll
            for (int m = 0; m < 2; ++m) {
                const int r = wm * 32 + m * 16 + rl;
                const int g = kc * 8 + ks * 4 + lh;
                ah[kc][ks][m] = *reinterpret_cast<const half8*>(
                    A + r * 512 + ((g ^ (r & 7)) << 4));
            }
    __syncthreads();    // staging region now free -> W-chunk arena

    const unsigned char* wplane = ws + WS_WH;
    auto issue = [&](int ct) {
        const int kcs = ct & 3;
        const int gtile = half * 32 + (ct >> 2);
        const unsigned char* src = wplane + (size_t)gtile * 65536 + (size_t)kcs * 16384;
        unsigned char* dst = A + kcs * 16384;
        #pragma unroll
        for (int i = 0; i < 4; ++i) {
            const int gran = wv * 256 + i * 64 + lane;
            __builtin_amdgcn_global_load_lds(
                (const __attribute__((address_space(1))) unsigned int*)(src + (size_t)gran * 16),
                (__attribute__((address_space(3))) unsigned int*)(dst + (size_t)gran * 16), 16, 0, 0);
        }
    };
    issue(0); issue(1); issue(2);

    float s1v[8], s2v[8];
    int   i1v[8];
    #pragma unroll
    for (int s = 0; s < 8; ++s) { s1v[s] = INFINITY; s2v[s] = INFINITY; i1v[s] = 0; }
    const float* wnp = (const float*)(ws + WS_WN);

    f32x4 acc[2][4];
    for (int t4 = 0; t4 < 32; ++t4) {
        #pragma unroll
        for (int kc = 0; kc < 4; ++kc) {
            const int ct = t4 * 4 + kc;     // chunk index 0..127, slot == kc
            if (t4 == 31) {
                if (kc == 2)      asm volatile("s_waitcnt vmcnt(4)" ::: "memory");
                else if (kc == 3) asm volatile("s_waitcnt vmcnt(0)" ::: "memory");
                else              asm volatile("s_waitcnt vmcnt(8)" ::: "memory");
            } else {
                asm volatile("s_waitcnt vmcnt(8)" ::: "memory");
            }
            __builtin_amdgcn_s_barrier();
            asm volatile("" ::: "memory");
            if (ct + 3 < 128) issue(ct + 3);

            if (kc == 0) {
                #pragma unroll
                for (int m = 0; m < 2; ++m)
                    #pragma unroll
                    for (int n = 0; n < 4; ++n) acc[m][n] = (f32x4)0.f;
            }
            const unsigned char* wb = A + kc * 16384;
            #pragma unroll
            for (int ks = 0; ks < 2; ++ks) {
                half8 bf[4];
                #pragma unroll
                for (int n = 0; n < 4; ++n) {
                    const int cc = wng * 64 + n * 16 + rl;
                    const int gg = ks * 4 + lh;
                    bf[n] = *reinterpret_cast<const half8*>(
                        wb + cc * 128 + ((gg ^ (cc & 7)) << 4));
                }
                #pragma unroll
                for (int m = 0; m < 2; ++m)
                    #pragma unroll
                    for (int n = 0; n < 4; ++n)
                        acc[m][n] = __builtin_amdgcn_mfma_f32_16x16x32_f16(
                            ah[kc][ks][m], bf[n], acc[m][n], 0, 0, 0);
            }
            if (kc == 3) {
                // tile epilogue: s = |w|^2 - 2*dot ; top-2 update (codes ascending)
                const int codebase = half * 4096 + t4 * 128 + wng * 64;
                #pragma unroll
                for (int n = 0; n < 4; ++n) {
                    const int code = codebase + n * 16 + rl;
                    const float wnv = wnp[code];
                    #pragma unroll
                    for (int m = 0; m < 2; ++m)
                        #pragma unroll
                        for (int rr = 0; rr < 4; ++rr) {
                            const int sl = m * 4 + rr;
                            float s = fmaf(-2.f, acc[m][n][rr], wnv);
                            bool lt = s < s1v[sl];
                            s2v[sl] = fminf(s2v[sl], fmaxf(s, s1v[sl]));
                            i1v[sl] = lt ? code : i1v[sl];
                            s1v[sl] = fminf(s1v[sl], s);
                        }
                }
            }
        }
    }

    // ---- cross-lane top-2 merge (16 lanes sharing a row) ----
    #pragma unroll
    for (int sl = 0; sl < 8; ++sl) {
        float v1 = s1v[sl], v2 = s2v[sl];
        int ii = i1v[sl];
        #pragma unroll
        for (int o = 8; o > 0; o >>= 1) {
            float ov1 = __shfl_xor(v1, o, 16);
            float ov2 = __shfl_xor(v2, o, 16);
            int   oi  = __shfl_xor(ii, o, 16);
            float ns2 = fminf(fmaxf(v1, ov1), fminf(v2, ov2));
            bool tk = (ov1 < v1) || (ov1 == v1 && oi < ii);
            v1 = tk ? ov1 : v1;
            ii = tk ? oi : ii;
            v2 = ns2;
        }
        if (rl == 0) {
            const int m = sl >> 2, rr = sl & 3;
            const int row = wm * 32 + m * 16 + lh * 4 + rr;
            MS1[row][wng] = v1; MI1[row][wng] = ii; MS2[row][wng] = v2;
        }
    }
    __syncthreads();
    if (t < 64) {
        float v0 = MS1[t][0], v1 = MS1[t][1];
        int   i0 = MI1[t][0], i1b = MI1[t][1];
        float s20 = MS2[t][0], s21 = MS2[t][1];
        bool tk = (v1 < v0) || (v1 == v0 && i1b < i0);
        float bs1 = tk ? v1 : v0;
        int bi = tk ? i1b : i0;
        float bs2 = fminf(fmaxf(v0, v1), fminf(s20, s21));
        const int grow = r0 + t;
        ((float*)(ws + WS_PV))[half * 16384 + grow] = bs1;
        ((int*)(ws + WS_PI))[half * 16384 + grow] = bi;
        ((float*)(ws + WS_PS2))[half * 16384 + grow] = bs2;
    }
}

// ============================================================================
// Merge halves -> preliminary idx; flag rows (gap < TH) -> FLG array + list.
// ============================================================================
__global__ __launch_bounds__(256)
void vq_flagmerge(unsigned char* __restrict__ ws)
{
    const int row = blockIdx.x * 256 + threadIdx.x;
    const float* PV  = (const float*)(ws + WS_PV);
    const int*   PI  = (const int*)(ws + WS_PI);
    const float* PS2 = (const float*)(ws + WS_PS2);
    float v0 = PV[row], v1 = PV[16384 + row];
    int   i0 = PI[row], i1 = PI[16384 + row];
    float s20 = PS2[row], s21 = PS2[16384 + row];
    bool tk = (v1 < v0) || (v1 == v0 && i1 < i0);
    float bs1 = tk ? v1 : v0;
    int bi = tk ? i1 : i0;
    float bs2 = fminf(fmaxf(v0, v1), fminf(s20, s21));
    ((int*)(ws + WS_IDX))[row] = bi;
    float th = ((const float*)(ws + WS_TH))[row];
    int fl = (bs2 - bs1 < th) ? 1 : 0;
    ((int*)(ws + WS_FLG))[row] = fl;
    if (fl) {
        unsigned p = atomicAdd((unsigned*)(ws + WS_CNT), 1u);
        ((int*)(ws + WS_LIST))[p] = row;
    }
}

// ============================================================================
// Exact-class 3-pass MFMA rescore of flagged rows, SLICED over codes.
// Item = (group of 64 flagged rows, slice of 1024 codes).
// dot = zh*wh + (zl*wh + zh*wl)/2048. Partials keyed by ROW -> deterministic.
// ============================================================================
__global__ __launch_bounds__(256, 1)
void vq_rescore3(const float* __restrict__ z, const float* __restrict__ w,
                 unsigned char* __restrict__ ws)
{
    // LDS: [0,32K) zh | [32K,64K) zl | [64K,128K) arena 2 slots x (wh16K+wl16K) | merge
    __shared__ __align__(16) unsigned char L[132352];
    float* MS1 = (float*)(L + 131072);           // [64][2]
    int*   MI1 = (int*)(L + 131072 + 512);       // [64][2]
    int*   rowsS = (int*)(L + 131072 + 1024);    // [64]

    const int t = threadIdx.x;
    const int lane = t & 63;
    const int wv = t >> 6;
    const int wm = wv >> 1, wng = wv & 1;
    const int rl = lane & 15, lh = lane >> 4;
    const unsigned cnt = *(const unsigned*)(ws + WS_CNT);
    if (cnt == 0) return;
    const unsigned ngroups = (cnt + 63u) >> 6;
    const unsigned items = ngroups * 8u;
    const int* list = (const int*)(ws + WS_LIST);
    const float* wnp = (const float*)(ws + WS_WN);
    float* RSV = (float*)(ws + WS_RSV);
    int*   RSI = (int*)(ws + WS_RSI);

    // stage one W chunk (128 codes x 64 d, fp32 -> hi/lo fp16) into arena slot
    auto stageW = [&](int cb, int kc, int slot) {
        unsigned char* whb = L + 65536 + slot * 32768;
        unsigned char* wlb = whb + 16384;
        #pragma unroll
        for (int i = 0; i < 4; ++i) {
            int task = i * 256 + t;
            int c = task >> 3, go = task & 7;
            const float* wsrc = w + (size_t)(cb + c) * 256 + kc * 64 + go * 8;
            float x[8];
            *reinterpret_cast<float4*>(x)     = *reinterpret_cast<const float4*>(wsrc);
            *reinterpret_cast<float4*>(x + 4) = *reinterpret_cast<const float4*>(wsrc + 4);
            half8 hi, lo;
            #pragma unroll
            for (int j = 0; j < 8; ++j) {
                float v = x[j];
                _Float16 h = (_Float16)v;
                hi[j] = h;
                lo[j] = (_Float16)((v - (float)h) * LSCALE);
            }
            const int woff = c * 128 + ((go ^ (c & 7)) << 4);
            *reinterpret_cast<half8*>(whb + woff) = hi;
            *reinterpret_cast<half8*>(wlb + woff) = lo;
        }
    };

    for (unsigned item = blockIdx.x; item < items; item += gridDim.x) {
        const unsigned g = item >> 3;
        const int s = (int)(item & 7u);

        if (t < 64) {
            unsigned li = g * 64u + (unsigned)t;
            rowsS[t] = list[li < cnt ? li : cnt - 1u];
        }
        __syncthreads();

        // ---- stage gathered z rows -> zh/zl (fp16, swizzled) ----
        {
            const int r = t & 63, qq = t >> 6;
            const int row = rowsS[r];
            const float* zb = z + ((size_t)(row >> 10) * 256 + qq * 64) * 1024 + (row & 1023);
            #pragma unroll
            for (int o = 0; o < 8; ++o) {
                half8 hi, lo;
                #pragma unroll
                for (int j = 0; j < 8; ++j) {
                    float v = zb[(size_t)(o * 8 + j) * 1024];
                    _Float16 h = (_Float16)v;
                    hi[j] = h;
                    lo[j] = (_Float16)((v - (float)h) * LSCALE);
                }
                const int go = qq * 8 + o;
                const int zoff = r * 512 + ((go ^ (r & 7)) << 4);
                *reinterpret_cast<half8*>(L + zoff) = hi;
                *reinterpret_cast<half8*>(L + 32768 + zoff) = lo;
            }
        }
        __syncthreads();

        // ---- hoist zh fragments ----
        half8 ah[4][2][2];
        #pragma unroll
        for (int kc = 0; kc < 4; ++kc)
            #pragma unroll
            for (int ks = 0; ks < 2; ++ks)
                #pragma unroll
                for (int m = 0; m < 2; ++m) {
                    const int r = wm * 32 + m * 16 + rl;
                    const int gg = kc * 8 + ks * 4 + lh;
                    ah[kc][ks][m] = *reinterpret_cast<const half8*>(
                        L + r * 512 + ((gg ^ (r & 7)) << 4));
                }

        float bv[8]; int bix[8];
        #pragma unroll
        for (int sl = 0; sl < 8; ++sl) { bv[sl] = INFINITY; bix[sl] = 0; }

        const int cbase0 = s * 1024;
        stageW(cbase0, 0, 0);
        __syncthreads();

        f32x4 accM[2][4], accC[2][4];
        for (int tile = 0; tile < 8; ++tile) {
            const int cb = cbase0 + tile * 128;
            #pragma unroll
            for (int kc = 0; kc < 4; ++kc) {
                // prefetch next chunk into the other slot (overlaps with MFMA)
                if (kc < 3)           stageW(cb, kc + 1, (kc + 1) & 1);
                else if (tile < 7)    stageW(cbase0 + (tile + 1) * 128, 0, 0);

                if (kc == 0) {
                    #pragma unroll
                    for (int m = 0; m < 2; ++m)
                        #pragma unroll
                        for (int n = 0; n < 4; ++n) {
                            accM[m][n] = (f32x4)0.f;
                            accC[m][n] = (f32x4)0.f;
                        }
                }
                const unsigned char* whb = L + 65536 + (kc & 1) * 32768;
                const unsigned char* wlb = whb + 16384;
                #pragma unroll
                for (int ks = 0; ks < 2; ++ks) {
                    half8 bfh[4], bfl[4];
                    #pragma unroll
                    for (int n = 0; n < 4; ++n) {
                        const int cc = wng * 64 + n * 16 + rl;
                        const int gg = ks * 4 + lh;
                        const int woff = cc * 128 + ((gg ^ (cc & 7)) << 4);
                        bfh[n] = *reinterpret_cast<const half8*>(whb + woff);
                        bfl[n] = *reinterpret_cast<const half8*>(wlb + woff);
                    }
                    #pragma unroll
                    for (int m = 0; m < 2; ++m)
                        #pragma unroll
                        for (int n = 0; n < 4; ++n)
                            accM[m][n] = __builtin_amdgcn_mfma_f32_16x16x32_f16(
                                ah[kc][ks][m], bfh[n], accM[m][n], 0, 0, 0);
                    #pragma unroll
                    for (int m = 0; m < 2; ++m) {
                        const int r = wm * 32 + m * 16 + rl;
                        const int gg = kc * 8 + ks * 4 + lh;
                        half8 al = *reinterpret_cast<const half8*>(
                            L + 32768 + r * 512 + ((gg ^ (r & 7)) << 4));
                        #pragma unroll
                        for (int n = 0; n < 4; ++n)
                            accC[m][n] = __builtin_amdgcn_mfma_f32_16x16x32_f16(
                                al, bfh[n], accC[m][n], 0, 0, 0);
                    }
                    #pragma unroll
                    for (int m = 0; m < 2; ++m)
                        #pragma unroll
                        for (int n = 0; n < 4; ++n)
                            accC[m][n] = __builtin_amdgcn_mfma_f32_16x16x32_f16(
                                ah[kc][ks][m], bfl[n], accC[m][n], 0, 0, 0);
                }

                if (kc == 3) {
                    // tile epilogue: top-1 (codes ascending, strict <)
                    #pragma unroll
                    for (int n = 0; n < 4; ++n) {
                        const int code = cb + wng * 64 + n * 16 + rl;
                        const float wnv = wnp[code];
                        #pragma unroll
                        for (int m = 0; m < 2; ++m)
                            #pragma unroll
                            for (int rr = 0; rr < 4; ++rr) {
                                const int sl = m * 4 + rr;
                                float dot = accM[m][n][rr] + accC[m][n][rr] * LINV;
                                float sc = fmaf(-2.f, dot, wnv);
                                if (sc < bv[sl]) { bv[sl] = sc; bix[sl] = code; }
                            }
                    }
                }
                __syncthreads();   // chunk boundary: staged data ready / arena reusable
            }
        }

        // ---- cross-lane top-1 reduce + write row-keyed partials ----
        #pragma unroll
        for (int sl = 0; sl < 8; ++sl) {
            float v = bv[sl]; int ix = bix[sl];
            #pragma unroll
            for (int o = 8; o > 0; o >>= 1) {
                float ov = __shfl_xor(v, o, 16);
                int   oi = __shfl_xor(ix, o, 16);
                if (ov < v || (ov == v && oi < ix)) { v = ov; ix = oi; }
            }
            if (rl == 0) {
                const int row = wm * 32 + (sl >> 2) * 16 + lh * 4 + (sl & 3);
                MS1[row * 2 + wng] = v; MI1[row * 2 + wng] = ix;
            }
        }
        __syncthreads();
        if (t < 64) {
            float v0 = MS1[t * 2 + 0], v1 = MS1[t * 2 + 1];
            int   i0 = MI1[t * 2 + 0], i1 = MI1[t * 2 + 1];
            bool tk = (v1 < v0) || (v1 == v0 && i1 < i0);
            float v = tk ? v1 : v0;
            int ix = tk ? i1 : i0;
            if (g * 64u + (unsigned)t < cnt) {
                const int row = rowsS[t];
                RSV[(size_t)row * 8 + s] = v;
                RSI[(size_t)row * 8 + s] = ix;
            }
        }
        __syncthreads();   // before next item's staging
    }
}

// ============================================================================
// Final indices (inline 8-slice merge for flagged rows -- r10-validated),
// gather z_q, direct loss partial sum.
// ============================================================================
__global__ __launch_bounds__(256)
void vq_gather(const float* __restrict__ z, const float* __restrict__ w,
               const unsigned char* __restrict__ ws, float* __restrict__ out,
               float* __restrict__ part)
{
    __shared__ int sidx[64];
    __shared__ float s4[4];
    const int t = threadIdx.x;
    const int n0 = blockIdx.x * 64;
    const int bb = n0 >> 10, rem0 = n0 & 1023;
    if (t < 64) {
        const int row = n0 + t;
        int ix = ((const int*)(ws + WS_IDX))[row];
        if (((const int*)(ws + WS_FLG))[row]) {
            const float* RSV = (const float*)(ws + WS_RSV);
            const int*   RSI = (const int*)(ws + WS_RSI);
            float bvv = RSV[(size_t)row * 8];
            int bi = RSI[(size_t)row * 8];
            #pragma unroll
            for (int s = 1; s < 8; ++s) {
                float v = RSV[(size_t)row * 8 + s];
                int ix2 = RSI[(size_t)row * 8 + s];
                if (v < bvv || (v == bvv && ix2 < bi)) { bvv = v; bi = ix2; }
            }
            ix = bi;
        }
        sidx[t] = ix;
        out[IDX_OFF + row] = (float)ix;
    }
    __syncthreads();
    const int r = t & 63, dq = t >> 6;
    const int idx = sidx[r];
    const float4* wrow = reinterpret_cast<const float4*>(w + (size_t)idx * 256 + dq * 64);
    const float* zb = z   + ((size_t)bb * 256 + dq * 64) * 1024 + rem0 + r;
    float*       ob = out + ((size_t)bb * 256 + dq * 64) * 1024 + rem0 + r;
    float acc = 0.f;
    #pragma unroll
    for (int d4 = 0; d4 < 16; ++d4) {
        float4 v = wrow[d4];
        float z0 = zb[(size_t)(d4 * 4 + 0) * 1024];
        float z1 = zb[(size_t)(d4 * 4 + 1) * 1024];
        float z2 = zb[(size_t)(d4 * 4 + 2) * 1024];
        float z3 = zb[(size_t)(d4 * 4 + 3) * 1024];
        ob[(size_t)(d4 * 4 + 0) * 1024] = v.x;
        ob[(size_t)(d4 * 4 + 1) * 1024] = v.y;
        ob[(size_t)(d4 * 4 + 2) * 1024] = v.z;
        ob[(size_t)(d4 * 4 + 3) * 1024] = v.w;
        float d0 = z0 - v.x, d1 = z1 - v.y, d2 = z2 - v.z, d3 = z3 - v.w;
        acc = fmaf(d0, d0, acc); acc = fmaf(d1, d1, acc);
        acc = fmaf(d2, d2, acc); acc = fmaf(d3, d3, acc);
    }
    #pragma unroll
    for (int o = 32; o > 0; o >>= 1) acc += __shfl_down(acc, o, 64);
    if ((t & 63) == 0) s4[t >> 6] = acc;
    __syncthreads();
    if (t == 0) part[blockIdx.x] = s4[0] + s4[1] + s4[2] + s4[3];
}

__global__ void vq_finish_kernel(const float* __restrict__ part, float* __restrict__ out)
{
    __shared__ float s4[4];
    int t = threadIdx.x;
    float v = part[t];
    #pragma unroll
    for (int off = 32; off > 0; off >>= 1) v += __shfl_down(v, off, 64);
    if ((t & 63) == 0) s4[t >> 6] = v;
    __syncthreads();
    if (t == 0) {
        float tot = s4[0] + s4[1] + s4[2] + s4[3];
        out[LOSS_OFF] = 0.25f * tot / ((float)NROWS * (float)DDIM);
    }
}

// ============================================================================
// Fallback (proven round-2 fp32 path) used only when ws_size is too small.
// ============================================================================
namespace fb {
constexpr int BM = 64, BN = 64, NCHUNK = KCODES / BN, BSTR = 257;
}
__global__ __launch_bounds__(256, 1)
void vq_main_fp32(const float* __restrict__ z, const float* __restrict__ w,
                  float* __restrict__ out, float* __restrict__ part)
{
    using namespace fb;
    __shared__ float At[DDIM][BM];
    __shared__ float Bt[BN][BSTR];
    __shared__ float zn_s[BM];
    __shared__ float wn4[BM][5];
    __shared__ float cmin[BM][17];
    __shared__ int   cidx[BM][17];
    __shared__ int   fidx_s[BM];

    const int t = threadIdx.x;
    const int n0 = blockIdx.x * BM;
    const int bb = n0 >> 10;
    const int rem0 = n0 & 1023;
    const float* zbase = z + (size_t)bb * DDIM * 1024 + rem0;

    #pragma unroll
    for (int it = 0; it < 16; ++it) {
        int tau = t + it * 256;
        int d = tau >> 4;
        int r4 = (tau & 15) << 2;
        float4 v = *reinterpret_cast<const float4*>(zbase + (size_t)d * 1024 + r4);
        *reinterpret_cast<float4*>(&At[d][r4]) = v;
    }
    __syncthreads();
    if (t < BM) {
        float s = 0.f;
        #pragma unroll 8
        for (int d = 0; d < DDIM; ++d) { float v = At[d][t]; s = fmaf(v, v, s); }
        zn_s[t] = s;
    }
    const int ty = t >> 4, tx = t & 15;
    float rmin[4]; int ridx[4];
    #pragma unroll
    for (int i = 0; i < 4; ++i) { rmin[i] = INFINITY; ridx[i] = 0; }

    for (int nc = 0; nc < NCHUNK; ++nc) {
        const float* wb = w + (size_t)nc * BN * DDIM;
        #pragma unroll
        for (int it = 0; it < 16; ++it) {
            int tau = t + it * 256;
            int k = tau >> 6;
            int d4 = (tau & 63) << 2;
            float4 v = *reinterpret_cast<const float4*>(wb + (size_t)k * DDIM + d4);
            Bt[k][d4 + 0] = v.x; Bt[k][d4 + 1] = v.y;
            Bt[k][d4 + 2] = v.z; Bt[k][d4 + 3] = v.w;
        }
        __syncthreads();
        {
            int k = t & 63, q = t >> 6;
            float s = 0.f;
            const int d0 = q * 64;
            #pragma unroll 8
            for (int d = 0; d < 64; ++d) { float v = Bt[k][d0 + d]; s = fmaf(v, v, s); }
            wn4[k][q] = s;
        }
        float acc[4][4];
        #pragma unroll
        for (int i = 0; i < 4; ++i)
            #pragma unroll
            for (int j = 0; j < 4; ++j) acc[i][j] = 0.f;
        #pragma unroll 8
        for (int kk = 0; kk < DDIM; ++kk) {
            float a[4], bvv[4];
            *reinterpret_cast<float4*>(a) =
                *reinterpret_cast<const float4*>(&At[kk][ty << 2]);
            #pragma unroll
            for (int j = 0; j < 4; ++j) bvv[j] = Bt[(tx << 2) + j][kk];
            #pragma unroll
            for (int i = 0; i < 4; ++i)
                #pragma unroll
                for (int j = 0; j < 4; ++j) acc[i][j] = fmaf(a[i], bvv[j], acc[i][j]);
        }
        __syncthreads();
        #pragma unroll
        for (int j = 0; j < 4; ++j) {
            int c = (tx << 2) + j;
            float wn = wn4[c][0] + wn4[c][1] + wn4[c][2] + wn4[c][3];
            int gidx = nc * BN + c;
            #pragma unroll
            for (int i = 0; i < 4; ++i) {
                float s = fmaf(-2.f, acc[i][j], wn);
                if (s < rmin[i]) { rmin[i] = s; ridx[i] = gidx; }
            }
        }
    }
    #pragma unroll
    for (int i = 0; i < 4; ++i) {
        cmin[(ty << 2) + i][tx] = rmin[i];
        cidx[(ty << 2) + i][tx] = ridx[i];
    }
    __syncthreads();
    float dist = 0.f;
    if (t < BM) {
        float bestv = cmin[t][0]; int besti = cidx[t][0];
        #pragma unroll
        for (int x = 1; x < 16; ++x) {
            float v = cmin[t][x]; int ix = cidx[t][x];
            if (v < bestv || (v == bestv && ix < besti)) { bestv = v; besti = ix; }
        }
        fidx_s[t] = besti;
        out[IDX_OFF + n0 + t] = (float)besti;
        dist = zn_s[t] + bestv;
    }
    if (t < 64) {
        #pragma unroll
        for (int off = 32; off > 0; off >>= 1) dist += __shfl_down(dist, off, 64);
        if (t == 0) part[blockIdx.x] = dist;
    }
    __syncthreads();
    {
        int r = t & 63, dq = t >> 6;
        int idx = fidx_s[r];
        const float4* wrow = reinterpret_cast<const float4*>(w + (size_t)idx * DDIM + dq * 64);
        float* obase = out + ((size_t)bb * DDIM + dq * 64) * 1024 + rem0 + r;
        #pragma unroll
        for (int d4 = 0; d4 < 16; ++d4) {
            float4 v = wrow[d4];
            obase[(size_t)(d4 * 4 + 0) * 1024] = v.x;
            obase[(size_t)(d4 * 4 + 1) * 1024] = v.y;
            obase[(size_t)(d4 * 4 + 2) * 1024] = v.z;
            obase[(size_t)(d4 * 4 + 3) * 1024] = v.w;
        }
    }
}

extern "C" void kernel_launch(void* const* d_in, const int* in_sizes, int n_in,
                              void* d_out, int out_size, void* d_ws, size_t ws_size,
                              hipStream_t stream) {
    const float* z = (const float*)d_in[0];
    const float* w = (const float*)d_in[1];
    float* out = (float*)d_out;
    if (ws_size >= WS_NEED) {
        unsigned char* ws = (unsigned char*)d_ws;
        float* part = (float*)(ws + WS_PART);
        vq_prep<<<1024, 256, 0, stream>>>(w, ws);
        vq_maxreduce<<<1, 256, 0, stream>>>(ws);
        vq_stage1<<<512, 256, 0, stream>>>(z, ws);
        vq_flagmerge<<<64, 256, 0, stream>>>(ws);
        vq_rescore3<<<2048, 256, 0, stream>>>(z, w, ws);
        vq_gather<<<256, 256, 0, stream>>>(z, w, ws, out, part);
        vq_finish_kernel<<<1, 256, 0, stream>>>(part, out);
    } else {
        float* part = (float*)d_ws;
        vq_main_fp32<<<NROWS / fb::BM, 256, 0, stream>>>(z, w, out, part);
        vq_finish_kernel<<<1, 256, 0, stream>>>(part, out);
    }
}

// Round 12
// 165.349 us; speedup vs baseline: 1.2506x; 1.0052x over previous
//
#include <hip/hip_runtime.h>
#include <math.h>

typedef _Float16 half8 __attribute__((ext_vector_type(8)));
typedef float f32x4 __attribute__((ext_vector_type(4)));

namespace {
constexpr int NROWS = 16384;        // 16*32*32
constexpr int DDIM  = 256;
constexpr int KCODES = 8192;
constexpr size_t LOSS_OFF = (size_t)16 * 256 * 32 * 32;  // 4194304
constexpr size_t IDX_OFF  = LOSS_OFF + 1;
constexpr float LSCALE = 2048.f;
constexpr float LINV   = 1.f / 2048.f;
// workspace layout (bytes)
constexpr size_t WS_WH   = 0;                    // 4 MB fp16 hi plane, swizzled
constexpr size_t WS_WN   = 4194304;              // 8192 f32 |w|^2
constexpr size_t WS_PV   = WS_WN + 32768;        // [2][16384] f32 best value per half
constexpr size_t WS_PI   = WS_PV + 131072;       // [2][16384] i32 best idx per half
constexpr size_t WS_PS2  = WS_PI + 131072;       // [2][16384] f32 2nd-best per half
constexpr size_t WS_THA  = WS_PS2 + 131072;      // 16384 f32 per-row |zh| (sqrt n2)
constexpr size_t WS_THB  = WS_THA + 65536;       // 16384 f32 per-row |z-zh| (sqrt e2)
constexpr size_t WS_IDX  = WS_THB + 65536;       // 16384 i32 preliminary indices
constexpr size_t WS_FLG  = WS_IDX + 65536;       // 16384 i32 flagged? (0/1)
constexpr size_t WS_LIST = WS_FLG + 65536;       // 16384 i32 flagged-row list
constexpr size_t WS_RSV  = WS_LIST + 65536;      // [16384][8] f32 rescore slice vals
constexpr size_t WS_RSI  = WS_RSV + 524288;      // [16384][8] i32 rescore slice idx
constexpr size_t WS_CNT  = WS_RSI + 524288;      // u32 flagged count
constexpr size_t WS_PART = WS_CNT + 256;         // 256 f32 loss partials
constexpr size_t WS_BMAX = WS_PART + 1024;       // [1024][2] f32 per-block maxima
constexpr size_t WS_NEED = WS_BMAX + 8192;       // ~6.0 MB
}

// ============================================================================
// Pre-convert codebook: fp32 -> fp16 hi plane (swizzled); |w|^2 per code;
// per-block maxima via plain stores (r6: same-address atomicMax cost ~130us).
// Block 0 zeroes the flag counter (ws poisoned only once pre-timing;
// r10-validated pattern). Plane: [tile=code>>7][kc=d>>6][c=code&127][g^(c&7)]
// ============================================================================
__global__ __launch_bounds__(256)
void vq_prep(const float* __restrict__ w, unsigned char* __restrict__ ws)
{
    __shared__ float rF[4], rS[4];
    if (blockIdx.x == 0 && threadIdx.x == 0) *(unsigned*)(ws + WS_CNT) = 0u;
    const int tau = blockIdx.x * 256 + threadIdx.x;   // 0..262143
    const int gcode = tau >> 5;                       // 0..8191
    const int sub = tau & 31;
    const int kc = sub >> 3, g = sub & 7;
    const float* src = w + (size_t)gcode * 256 + kc * 64 + g * 8;
    float x[8];
    *reinterpret_cast<float4*>(x)     = *reinterpret_cast<const float4*>(src);
    *reinterpret_cast<float4*>(x + 4) = *reinterpret_cast<const float4*>(src + 4);
    half8 hi;
    float sq = 0.f, fq = 0.f;
    #pragma unroll
    for (int j = 0; j < 8; ++j) {
        float v = x[j];
        sq = fmaf(v, v, sq);
        _Float16 h = (_Float16)v;
        hi[j] = h;
        float res = v - (float)h;
        fq = fmaf(res, res, fq);
    }
    const size_t off = (size_t)(gcode >> 7) * 65536 + (size_t)kc * 16384
                     + (size_t)(gcode & 127) * 128 + (size_t)((g ^ (gcode & 7)) << 4);
    *reinterpret_cast<half8*>(ws + WS_WH + off) = hi;
    #pragma unroll
    for (int o = 16; o > 0; o >>= 1) {
        sq += __shfl_down(sq, o, 32);
        fq += __shfl_down(fq, o, 32);
    }
    if (sub == 0) ((float*)(ws + WS_WN))[gcode] = sq;
    float sqc = (sub == 0) ? sq : 0.f;
    float fqc = (sub == 0) ? fq : 0.f;
    #pragma unroll
    for (int o = 32; o > 0; o >>= 1) {
        sqc = fmaxf(sqc, __shfl_xor(sqc, o, 64));
        fqc = fmaxf(fqc, __shfl_xor(fqc, o, 64));
    }
    if ((threadIdx.x & 63) == 0) { rF[threadIdx.x >> 6] = fqc; rS[threadIdx.x >> 6] = sqc; }
    __syncthreads();
    if (threadIdx.x == 0) {
        float* bm = (float*)(ws + WS_BMAX);
        bm[blockIdx.x * 2]     = fmaxf(fmaxf(rF[0], rF[1]), fmaxf(rF[2], rF[3]));
        bm[blockIdx.x * 2 + 1] = fmaxf(fmaxf(rS[0], rS[1]), fmaxf(rS[2], rS[3]));
    }
}

// ============================================================================
// Stage 1 -- r9/r11-proven config (98 us, MfmaUtil 30, VGPR 104, WRITE
// ~0.45MB). Do NOT touch: launch_bounds(256,2) [r8/r10: tighter occupancy
// bounds spill ah[] -> 13-64MB scratch]; no setprio [r7: lockstep structure,
// 98->111]. Only change vs r11: writes per-row A=|zh|, B=|z-zh| instead of
// TH (drops the FMAX/WMAX dependency; maxreduce launch deleted).
// Block = 256 thr (4 waves, 2M x 2N), 64 rows x 4096 codes (half).
// grid 512: rg = bid>>1, half = bid&1. 4x16KB arena, vmcnt 8/4/0.
// ============================================================================
__global__ __launch_bounds__(256, 2)
void vq_stage1(const float* __restrict__ z, unsigned char* __restrict__ ws)
{
    __shared__ __align__(16) unsigned char A[65536];
    __shared__ float MS1[64][2];
    __shared__ int   MI1[64][2];
    __shared__ float MS2[64][2];
    __shared__ float STE[64][4];
    __shared__ float STN[64][4];

    const int t = threadIdx.x;
    const int lane = t & 63;
    const int wv = t >> 6;          // 0..3
    const int wm = wv >> 1;         // row group of 32
    const int wng = wv & 1;         // code group of 64
    const int rl = lane & 15, lh = lane >> 4;
    const int bid = blockIdx.x;
    const int rg = bid >> 1;
    const int half = bid & 1;
    const int r0 = rg * 64;
    const int bb = r0 >> 10;
    const int rem0 = r0 & 1023;
    const float* zbase = z + (size_t)bb * 256 * 1024 + rem0;

    // ---- stage zh (fp16, swizzled) + per-row residual/norm partials ----
    {
        const int r = t & 63;
        const int ob = t >> 6;               // 0..3 -> d range [ob*64, ob*64+64)
        float e2 = 0.f, n2 = 0.f;
        #pragma unroll
        for (int i = 0; i < 8; ++i) {
            const int o = ob * 8 + i;        // k-octet
            half8 hi;
            #pragma unroll
            for (int j = 0; j < 8; ++j) {
                float v = zbase[(size_t)(o * 8 + j) * 1024 + r];
                _Float16 h = (_Float16)v;
                hi[j] = h;
                float res = v - (float)h;
                e2 = fmaf(res, res, e2);
                n2 = fmaf((float)h, (float)h, n2);
            }
            *reinterpret_cast<half8*>(A + r * 512 + ((o ^ (r & 7)) << 4)) = hi;
        }
        STE[r][ob] = e2;
        STN[r][ob] = n2;
    }
    __syncthreads();

    // ---- per-row norm components (written once, by half==0 blocks) ----
    if (t < 64 && half == 0) {
        float e2 = STE[t][0] + STE[t][1] + STE[t][2] + STE[t][3];
        float n2 = STN[t][0] + STN[t][1] + STN[t][2] + STN[t][3];
        ((float*)(ws + WS_THA))[r0 + t] = sqrtf(n2);
        ((float*)(ws + WS_THB))[r0 + t] = sqrtf(e2);
    }

    // ---- hoist zh fragments to registers: ah[kc][ks][m] ----
    half8 ah[4][2][2];
    #pragma unroll
    for (int kc = 0; kc < 4; ++kc)
        #pragma unroll
        for (int ks = 0; ks < 2; ++ks)
            #pragma unroll
            for (int m = 0; m < 2; ++m) {
                const int r = wm * 32 + m * 16 + rl;
                const int g = kc * 8 + ks * 4 + lh;
                ah[kc][ks][m] = *reinterpret_cast<const half8*>(
                    A + r * 512 + ((g ^ (r & 7)) << 4));
            }
    __syncthreads();    // staging region now free -> W-chunk arena

    const unsigned char* wplane = ws + WS_WH;
    auto issue = [&](int ct) {
        const int kcs = ct & 3;
        const int gtile = half * 32 + (ct >> 2);
        const unsigned char* src = wplane + (size_t)gtile * 65536 + (size_t)kcs * 16384;
        unsigned char* dst = A + kcs * 16384;
        #pragma unroll
        for (int i = 0; i < 4; ++i) {
            const int gran = wv * 256 + i * 64 + lane;
            __builtin_amdgcn_global_load_lds(
                (const __attribute__((address_space(1))) unsigned int*)(src + (size_t)gran * 16),
                (__attribute__((address_space(3))) unsigned int*)(dst + (size_t)gran * 16), 16, 0, 0);
        }
    };
    issue(0); issue(1); issue(2);

    float s1v[8], s2v[8];
    int   i1v[8];
    #pragma unroll
    for (int s = 0; s < 8; ++s) { s1v[s] = INFINITY; s2v[s] = INFINITY; i1v[s] = 0; }
    const float* wnp = (const float*)(ws + WS_WN);

    f32x4 acc[2][4];
    for (int t4 = 0; t4 < 32; ++t4) {
        #pragma unroll
        for (int kc = 0; kc < 4; ++kc) {
            const int ct = t4 * 4 + kc;     // chunk index 0..127, slot == kc
            if (t4 == 31) {
                if (kc == 2)      asm volatile("s_waitcnt vmcnt(4)" ::: "memory");
                else if (kc == 3) asm volatile("s_waitcnt vmcnt(0)" ::: "memory");
                else              asm volatile("s_waitcnt vmcnt(8)" ::: "memory");
            } else {
                asm volatile("s_waitcnt vmcnt(8)" ::: "memory");
            }
            __builtin_amdgcn_s_barrier();
            asm volatile("" ::: "memory");
            if (ct + 3 < 128) issue(ct + 3);

            if (kc == 0) {
                #pragma unroll
                for (int m = 0; m < 2; ++m)
                    #pragma unroll
                    for (int n = 0; n < 4; ++n) acc[m][n] = (f32x4)0.f;
            }
            const unsigned char* wb = A + kc * 16384;
            #pragma unroll
            for (int ks = 0; ks < 2; ++ks) {
                half8 bf[4];
                #pragma unroll
                for (int n = 0; n < 4; ++n) {
                    const int cc = wng * 64 + n * 16 + rl;
                    const int gg = ks * 4 + lh;
                    bf[n] = *reinterpret_cast<const half8*>(
                        wb + cc * 128 + ((gg ^ (cc & 7)) << 4));
                }
                #pragma unroll
                for (int m = 0; m < 2; ++m)
                    #pragma unroll
                    for (int n = 0; n < 4; ++n)
                        acc[m][n] = __builtin_amdgcn_mfma_f32_16x16x32_f16(
                            ah[kc][ks][m], bf[n], acc[m][n], 0, 0, 0);
            }
            if (kc == 3) {
                // tile epilogue: s = |w|^2 - 2*dot ; top-2 update (codes ascending)
                const int codebase = half * 4096 + t4 * 128 + wng * 64;
                #pragma unroll
                for (int n = 0; n < 4; ++n) {
                    const int code = codebase + n * 16 + rl;
                    const float wnv = wnp[code];
                    #pragma unroll
                    for (int m = 0; m < 2; ++m)
                        #pragma unroll
                        for (int rr = 0; rr < 4; ++rr) {
                            const int sl = m * 4 + rr;
                            float s = fmaf(-2.f, acc[m][n][rr], wnv);
                            bool lt = s < s1v[sl];
                            s2v[sl] = fminf(s2v[sl], fmaxf(s, s1v[sl]));
                            i1v[sl] = lt ? code : i1v[sl];
                            s1v[sl] = fminf(s1v[sl], s);
                        }
                }
            }
        }
    }

    // ---- cross-lane top-2 merge (16 lanes sharing a row) ----
    #pragma unroll
    for (int sl = 0; sl < 8; ++sl) {
        float v1 = s1v[sl], v2 = s2v[sl];
        int ii = i1v[sl];
        #pragma unroll
        for (int o = 8; o > 0; o >>= 1) {
            float ov1 = __shfl_xor(v1, o, 16);
            float ov2 = __shfl_xor(v2, o, 16);
            int   oi  = __shfl_xor(ii, o, 16);
            float ns2 = fminf(fmaxf(v1, ov1), fminf(v2, ov2));
            bool tk = (ov1 < v1) || (ov1 == v1 && oi < ii);
            v1 = tk ? ov1 : v1;
            ii = tk ? oi : ii;
            v2 = ns2;
        }
        if (rl == 0) {
            const int m = sl >> 2, rr = sl & 3;
            const int row = wm * 32 + m * 16 + lh * 4 + rr;
            MS1[row][wng] = v1; MI1[row][wng] = ii; MS2[row][wng] = v2;
        }
    }
    __syncthreads();
    if (t < 64) {
        float v0 = MS1[t][0], v1 = MS1[t][1];
        int   i0 = MI1[t][0], i1b = MI1[t][1];
        float s20 = MS2[t][0], s21 = MS2[t][1];
        bool tk = (v1 < v0) || (v1 == v0 && i1b < i0);
        float bs1 = tk ? v1 : v0;
        int bi = tk ? i1b : i0;
        float bs2 = fminf(fmaxf(v0, v1), fminf(s20, s21));
        const int grow = r0 + t;
        ((float*)(ws + WS_PV))[half * 16384 + grow] = bs1;
        ((int*)(ws + WS_PI))[half * 16384 + grow] = bi;
        ((float*)(ws + WS_PS2))[half * 16384 + grow] = bs2;
    }
}

// ============================================================================
// Merge halves -> preliminary idx; flag rows (gap < TH) -> FLG array + list.
// Absorbs the old maxreduce: each block redundantly reduces the 2KB BMAX
// array (same reduction order -> bitwise-identical Fm/Wm -> identical TH).
// ============================================================================
__global__ __launch_bounds__(256)
void vq_flagmerge(unsigned char* __restrict__ ws)
{
    __shared__ float sF[4], sS[4];
    const int t = threadIdx.x;
    const float* bm = (const float*)(ws + WS_BMAX);
    float f = 0.f, s = 0.f;
    #pragma unroll
    for (int i = 0; i < 4; ++i) {
        f = fmaxf(f, bm[(t + i * 256) * 2]);
        s = fmaxf(s, bm[(t + i * 256) * 2 + 1]);
    }
    #pragma unroll
    for (int o = 32; o > 0; o >>= 1) {
        f = fmaxf(f, __shfl_xor(f, o, 64));
        s = fmaxf(s, __shfl_xor(s, o, 64));
    }
    if ((t & 63) == 0) { sF[t >> 6] = f; sS[t >> 6] = s; }
    __syncthreads();
    const float Fm = sqrtf(fmaxf(fmaxf(sF[0], sF[1]), fmaxf(sF[2], sF[3])));
    const float Wm = sqrtf(fmaxf(fmaxf(sS[0], sS[1]), fmaxf(sS[2], sS[3])));

    const int row = blockIdx.x * 256 + t;
    const float* PV  = (const float*)(ws + WS_PV);
    const int*   PI  = (const int*)(ws + WS_PI);
    const float* PS2 = (const float*)(ws + WS_PS2);
    float v0 = PV[row], v1 = PV[16384 + row];
    int   i0 = PI[row], i1 = PI[16384 + row];
    float s20 = PS2[row], s21 = PS2[16384 + row];
    bool tk = (v1 < v0) || (v1 == v0 && i1 < i0);
    float bs1 = tk ? v1 : v0;
    int bi = tk ? i1 : i0;
    float bs2 = fminf(fmaxf(v0, v1), fminf(s20, s21));
    ((int*)(ws + WS_IDX))[row] = bi;
    float th = 0.75f * (((const float*)(ws + WS_THA))[row] * Fm
                      + ((const float*)(ws + WS_THB))[row] * Wm) + 0.03f;
    int fl = (bs2 - bs1 < th) ? 1 : 0;
    ((int*)(ws + WS_FLG))[row] = fl;
    if (fl) {
        unsigned p = atomicAdd((unsigned*)(ws + WS_CNT), 1u);
        ((int*)(ws + WS_LIST))[p] = row;
    }
}

// ============================================================================
// Exact-class 3-pass MFMA rescore of flagged rows, SLICED over codes.
// Item = (group of 64 flagged rows, slice of 1024 codes).
// dot = zh*wh + (zl*wh + zh*wl)/2048. Partials keyed by ROW -> deterministic.
// ============================================================================
__global__ __launch_bounds__(256, 1)
void vq_rescore3(const float* __restrict__ z, const float* __restrict__ w,
                 unsigned char* __restrict__ ws)
{
    // LDS: [0,32K) zh | [32K,64K) zl | [64K,128K) arena 2 slots x (wh16K+wl16K) | merge
    __shared__ __align__(16) unsigned char L[132352];
    float* MS1 = (float*)(L + 131072);           // [64][2]
    int*   MI1 = (int*)(L + 131072 + 512);       // [64][2]
    int*   rowsS = (int*)(L + 131072 + 1024);    // [64]

    const int t = threadIdx.x;
    const int lane = t & 63;
    const int wv = t >> 6;
    const int wm = wv >> 1, wng = wv & 1;
    const int rl = lane & 15, lh = lane >> 4;
    const unsigned cnt = *(const unsigned*)(ws + WS_CNT);
    if (cnt == 0) return;
    const unsigned ngroups = (cnt + 63u) >> 6;
    const unsigned items = ngroups * 8u;
    const int* list = (const int*)(ws + WS_LIST);
    const float* wnp = (const float*)(ws + WS_WN);
    float* RSV = (float*)(ws + WS_RSV);
    int*   RSI = (int*)(ws + WS_RSI);

    // stage one W chunk (128 codes x 64 d, fp32 -> hi/lo fp16) into arena slot
    auto stageW = [&](int cb, int kc, int slot) {
        unsigned char* whb = L + 65536 + slot * 32768;
        unsigned char* wlb = whb + 16384;
        #pragma unroll
        for (int i = 0; i < 4; ++i) {
            int task = i * 256 + t;
            int c = task >> 3, go = task & 7;
            const float* wsrc = w + (size_t)(cb + c) * 256 + kc * 64 + go * 8;
            float x[8];
            *reinterpret_cast<float4*>(x)     = *reinterpret_cast<const float4*>(wsrc);
            *reinterpret_cast<float4*>(x + 4) = *reinterpret_cast<const float4*>(wsrc + 4);
            half8 hi, lo;
            #pragma unroll
            for (int j = 0; j < 8; ++j) {
                float v = x[j];
                _Float16 h = (_Float16)v;
                hi[j] = h;
                lo[j] = (_Float16)((v - (float)h) * LSCALE);
            }
            const int woff = c * 128 + ((go ^ (c & 7)) << 4);
            *reinterpret_cast<half8*>(whb + woff) = hi;
            *reinterpret_cast<half8*>(wlb + woff) = lo;
        }
    };

    for (unsigned item = blockIdx.x; item < items; item += gridDim.x) {
        const unsigned g = item >> 3;
        const int s = (int)(item & 7u);

        if (t < 64) {
            unsigned li = g * 64u + (unsigned)t;
            rowsS[t] = list[li < cnt ? li : cnt - 1u];
        }
        __syncthreads();

        // ---- stage gathered z rows -> zh/zl (fp16, swizzled) ----
        {
            const int r = t & 63, qq = t >> 6;
            const int row = rowsS[r];
            const float* zb = z + ((size_t)(row >> 10) * 256 + qq * 64) * 1024 + (row & 1023);
            #pragma unroll
            for (int o = 0; o < 8; ++o) {
                half8 hi, lo;
                #pragma unroll
                for (int j = 0; j < 8; ++j) {
                    float v = zb[(size_t)(o * 8 + j) * 1024];
                    _Float16 h = (_Float16)v;
                    hi[j] = h;
                    lo[j] = (_Float16)((v - (float)h) * LSCALE);
                }
                const int go = qq * 8 + o;
                const int zoff = r * 512 + ((go ^ (r & 7)) << 4);
                *reinterpret_cast<half8*>(L + zoff) = hi;
                *reinterpret_cast<half8*>(L + 32768 + zoff) = lo;
            }
        }
        __syncthreads();

        // ---- hoist zh fragments ----
        half8 ah[4][2][2];
        #pragma unroll
        for (int kc = 0; kc < 4; ++kc)
            #pragma unroll
            for (int ks = 0; ks < 2; ++ks)
                #pragma unroll
                for (int m = 0; m < 2; ++m) {
                    const int r = wm * 32 + m * 16 + rl;
                    const int gg = kc * 8 + ks * 4 + lh;
                    ah[kc][ks][m] = *reinterpret_cast<const half8*>(
                        L + r * 512 + ((gg ^ (r & 7)) << 4));
                }

        float bv[8]; int bix[8];
        #pragma unroll
        for (int sl = 0; sl < 8; ++sl) { bv[sl] = INFINITY; bix[sl] = 0; }

        const int cbase0 = s * 1024;
        stageW(cbase0, 0, 0);
        __syncthreads();

        f32x4 accM[2][4], accC[2][4];
        for (int tile = 0; tile < 8; ++tile) {
            const int cb = cbase0 + tile * 128;
            #pragma unroll
            for (int kc = 0; kc < 4; ++kc) {
                // prefetch next chunk into the other slot (overlaps with MFMA)
                if (kc < 3)           stageW(cb, kc + 1, (kc + 1) & 1);
                else if (tile < 7)    stageW(cbase0 + (tile + 1) * 128, 0, 0);

                if (kc == 0) {
                    #pragma unroll
                    for (int m = 0; m < 2; ++m)
                        #pragma unroll
                        for (int n = 0; n < 4; ++n) {
                            accM[m][n] = (f32x4)0.f;
                            accC[m][n] = (f32x4)0.f;
                        }
                }
                const unsigned char* whb = L + 65536 + (kc & 1) * 32768;
                const unsigned char* wlb = whb + 16384;
                #pragma unroll
                for (int ks = 0; ks < 2; ++ks) {
                    half8 bfh[4], bfl[4];
                    #pragma unroll
                    for (int n = 0; n < 4; ++n) {
                        const int cc = wng * 64 + n * 16 + rl;
                        const int gg = ks * 4 + lh;
                        const int woff = cc * 128 + ((gg ^ (cc & 7)) << 4);
                        bfh[n] = *reinterpret_cast<const half8*>(whb + woff);
                        bfl[n] = *reinterpret_cast<const half8*>(wlb + woff);
                    }
                    #pragma unroll
                    for (int m = 0; m < 2; ++m)
                        #pragma unroll
                        for (int n = 0; n < 4; ++n)
                            accM[m][n] = __builtin_amdgcn_mfma_f32_16x16x32_f16(
                                ah[kc][ks][m], bfh[n], accM[m][n], 0, 0, 0);
                    #pragma unroll
                    for (int m = 0; m < 2; ++m) {
                        const int r = wm * 32 + m * 16 + rl;
                        const int gg = kc * 8 + ks * 4 + lh;
                        half8 al = *reinterpret_cast<const half8*>(
                            L + 32768 + r * 512 + ((gg ^ (r & 7)) << 4));
                        #pragma unroll
                        for (int n = 0; n < 4; ++n)
                            accC[m][n] = __builtin_amdgcn_mfma_f32_16x16x32_f16(
                                al, bfh[n], accC[m][n], 0, 0, 0);
                    }
                    #pragma unroll
                    for (int m = 0; m < 2; ++m)
                        #pragma unroll
                        for (int n = 0; n < 4; ++n)
                            accC[m][n] = __builtin_amdgcn_mfma_f32_16x16x32_f16(
                                ah[kc][ks][m], bfl[n], accC[m][n], 0, 0, 0);
                }

                if (kc == 3) {
                    // tile epilogue: top-1 (codes ascending, strict <)
                    #pragma unroll
                    for (int n = 0; n < 4; ++n) {
                        const int code = cb + wng * 64 + n * 16 + rl;
                        const float wnv = wnp[code];
                        #pragma unroll
                        for (int m = 0; m < 2; ++m)
                            #pragma unroll
                            for (int rr = 0; rr < 4; ++rr) {
                                const int sl = m * 4 + rr;
                                float dot = accM[m][n][rr] + accC[m][n][rr] * LINV;
                                float sc = fmaf(-2.f, dot, wnv);
                                if (sc < bv[sl]) { bv[sl] = sc; bix[sl] = code; }
                            }
                    }
                }
                __syncthreads();   // chunk boundary: staged data ready / arena reusable
            }
        }

        // ---- cross-lane top-1 reduce + write row-keyed partials ----
        #pragma unroll
        for (int sl = 0; sl < 8; ++sl) {
            float v = bv[sl]; int ix = bix[sl];
            #pragma unroll
            for (int o = 8; o > 0; o >>= 1) {
                float ov = __shfl_xor(v, o, 16);
                int   oi = __shfl_xor(ix, o, 16);
                if (ov < v || (ov == v && oi < ix)) { v = ov; ix = oi; }
            }
            if (rl == 0) {
                const int row = wm * 32 + (sl >> 2) * 16 + lh * 4 + (sl & 3);
                MS1[row * 2 + wng] = v; MI1[row * 2 + wng] = ix;
            }
        }
        __syncthreads();
        if (t < 64) {
            float v0 = MS1[t * 2 + 0], v1 = MS1[t * 2 + 1];
            int   i0 = MI1[t * 2 + 0], i1 = MI1[t * 2 + 1];
            bool tk = (v1 < v0) || (v1 == v0 && i1 < i0);
            float v = tk ? v1 : v0;
            int ix = tk ? i1 : i0;
            if (g * 64u + (unsigned)t < cnt) {
                const int row = rowsS[t];
                RSV[(size_t)row * 8 + s] = v;
                RSI[(size_t)row * 8 + s] = ix;
            }
        }
        __syncthreads();   // before next item's staging
    }
}

// ============================================================================
// Final indices (inline 8-slice merge for flagged rows -- r10-validated),
// gather z_q, direct loss partial sum.
// ============================================================================
__global__ __launch_bounds__(256)
void vq_gather(const float* __restrict__ z, const float* __restrict__ w,
               const unsigned char* __restrict__ ws, float* __restrict__ out,
               float* __restrict__ part)
{
    __shared__ int sidx[64];
    __shared__ float s4[4];
    const int t = threadIdx.x;
    const int n0 = blockIdx.x * 64;
    const int bb = n0 >> 10, rem0 = n0 & 1023;
    if (t < 64) {
        const int row = n0 + t;
        int ix = ((const int*)(ws + WS_IDX))[row];
        if (((const int*)(ws + WS_FLG))[row]) {
            const float* RSV = (const float*)(ws + WS_RSV);
            const int*   RSI = (const int*)(ws + WS_RSI);
            float bvv = RSV[(size_t)row * 8];
            int bi = RSI[(size_t)row * 8];
            #pragma unroll
            for (int s = 1; s < 8; ++s) {
                float v = RSV[(size_t)row * 8 + s];
                int ix2 = RSI[(size_t)row * 8 + s];
                if (v < bvv || (v == bvv && ix2 < bi)) { bvv = v; bi = ix2; }
            }
            ix = bi;
        }
        sidx[t] = ix;
        out[IDX_OFF + row] = (float)ix;
    }
    __syncthreads();
    const int r = t & 63, dq = t >> 6;
    const int idx = sidx[r];
    const float4* wrow = reinterpret_cast<const float4*>(w + (size_t)idx * 256 + dq * 64);
    const float* zb = z   + ((size_t)bb * 256 + dq * 64) * 1024 + rem0 + r;
    float*       ob = out + ((size_t)bb * 256 + dq * 64) * 1024 + rem0 + r;
    float acc = 0.f;
    #pragma unroll
    for (int d4 = 0; d4 < 16; ++d4) {
        float4 v = wrow[d4];
        float z0 = zb[(size_t)(d4 * 4 + 0) * 1024];
        float z1 = zb[(size_t)(d4 * 4 + 1) * 1024];
        float z2 = zb[(size_t)(d4 * 4 + 2) * 1024];
        float z3 = zb[(size_t)(d4 * 4 + 3) * 1024];
        ob[(size_t)(d4 * 4 + 0) * 1024] = v.x;
        ob[(size_t)(d4 * 4 + 1) * 1024] = v.y;
        ob[(size_t)(d4 * 4 + 2) * 1024] = v.z;
        ob[(size_t)(d4 * 4 + 3) * 1024] = v.w;
        float d0 = z0 - v.x, d1 = z1 - v.y, d2 = z2 - v.z, d3 = z3 - v.w;
        acc = fmaf(d0, d0, acc); acc = fmaf(d1, d1, acc);
        acc = fmaf(d2, d2, acc); acc = fmaf(d3, d3, acc);
    }
    #pragma unroll
    for (int o = 32; o > 0; o >>= 1) acc += __shfl_down(acc, o, 64);
    if ((t & 63) == 0) s4[t >> 6] = acc;
    __syncthreads();
    if (t == 0) part[blockIdx.x] = s4[0] + s4[1] + s4[2] + s4[3];
}

__global__ void vq_finish_kernel(const float* __restrict__ part, float* __restrict__ out)
{
    __shared__ float s4[4];
    int t = threadIdx.x;
    float v = part[t];
    #pragma unroll
    for (int off = 32; off > 0; off >>= 1) v += __shfl_down(v, off, 64);
    if ((t & 63) == 0) s4[t >> 6] = v;
    __syncthreads();
    if (t == 0) {
        float tot = s4[0] + s4[1] + s4[2] + s4[3];
        out[LOSS_OFF] = 0.25f * tot / ((float)NROWS * (float)DDIM);
    }
}

// ============================================================================
// Fallback (proven round-2 fp32 path) used only when ws_size is too small.
// ============================================================================
namespace fb {
constexpr int BM = 64, BN = 64, NCHUNK = KCODES / BN, BSTR = 257;
}
__global__ __launch_bounds__(256, 1)
void vq_main_fp32(const float* __restrict__ z, const float* __restrict__ w,
                  float* __restrict__ out, float* __restrict__ part)
{
    using namespace fb;
    __shared__ float At[DDIM][BM];
    __shared__ float Bt[BN][BSTR];
    __shared__ float zn_s[BM];
    __shared__ float wn4[BM][5];
    __shared__ float cmin[BM][17];
    __shared__ int   cidx[BM][17];
    __shared__ int   fidx_s[BM];

    const int t = threadIdx.x;
    const int n0 = blockIdx.x * BM;
    const int bb = n0 >> 10;
    const int rem0 = n0 & 1023;
    const float* zbase = z + (size_t)bb * DDIM * 1024 + rem0;

    #pragma unroll
    for (int it = 0; it < 16; ++it) {
        int tau = t + it * 256;
        int d = tau >> 4;
        int r4 = (tau & 15) << 2;
        float4 v = *reinterpret_cast<const float4*>(zbase + (size_t)d * 1024 + r4);
        *reinterpret_cast<float4*>(&At[d][r4]) = v;
    }
    __syncthreads();
    if (t < BM) {
        float s = 0.f;
        #pragma unroll 8
        for (int d = 0; d < DDIM; ++d) { float v = At[d][t]; s = fmaf(v, v, s); }
        zn_s[t] = s;
    }
    const int ty = t >> 4, tx = t & 15;
    float rmin[4]; int ridx[4];
    #pragma unroll
    for (int i = 0; i < 4; ++i) { rmin[i] = INFINITY; ridx[i] = 0; }

    for (int nc = 0; nc < NCHUNK; ++nc) {
        const float* wb = w + (size_t)nc * BN * DDIM;
        #pragma unroll
        for (int it = 0; it < 16; ++it) {
            int tau = t + it * 256;
            int k = tau >> 6;
            int d4 = (tau & 63) << 2;
            float4 v = *reinterpret_cast<const float4*>(wb + (size_t)k * DDIM + d4);
            Bt[k][d4 + 0] = v.x; Bt[k][d4 + 1] = v.y;
            Bt[k][d4 + 2] = v.z; Bt[k][d4 + 3] = v.w;
        }
        __syncthreads();
        {
            int k = t & 63, q = t >> 6;
            float s = 0.f;
            const int d0 = q * 64;
            #pragma unroll 8
            for (int d = 0; d < 64; ++d) { float v = Bt[k][d0 + d]; s = fmaf(v, v, s); }
            wn4[k][q] = s;
        }
        float acc[4][4];
        #pragma unroll
        for (int i = 0; i < 4; ++i)
            #pragma unroll
            for (int j = 0; j < 4; ++j) acc[i][j] = 0.f;
        #pragma unroll 8
        for (int kk = 0; kk < DDIM; ++kk) {
            float a[4], bvv[4];
            *reinterpret_cast<float4*>(a) =
                *reinterpret_cast<const float4*>(&At[kk][ty << 2]);
            #pragma unroll
            for (int j = 0; j < 4; ++j) bvv[j] = Bt[(tx << 2) + j][kk];
            #pragma unroll
            for (int i = 0; i < 4; ++i)
                #pragma unroll
                for (int j = 0; j < 4; ++j) acc[i][j] = fmaf(a[i], bvv[j], acc[i][j]);
        }
        __syncthreads();
        #pragma unroll
        for (int j = 0; j < 4; ++j) {
            int c = (tx << 2) + j;
            float wn = wn4[c][0] + wn4[c][1] + wn4[c][2] + wn4[c][3];
            int gidx = nc * BN + c;
            #pragma unroll
            for (int i = 0; i < 4; ++i) {
                float s = fmaf(-2.f, acc[i][j], wn);
                if (s < rmin[i]) { rmin[i] = s; ridx[i] = gidx; }
            }
        }
    }
    #pragma unroll
    for (int i = 0; i < 4; ++i) {
        cmin[(ty << 2) + i][tx] = rmin[i];
        cidx[(ty << 2) + i][tx] = ridx[i];
    }
    __syncthreads();
    float dist = 0.f;
    if (t < BM) {
        float bestv = cmin[t][0]; int besti = cidx[t][0];
        #pragma unroll
        for (int x = 1; x < 16; ++x) {
            float v = cmin[t][x]; int ix = cidx[t][x];
            if (v < bestv || (v == bestv && ix < besti)) { bestv = v; besti = ix; }
        }
        fidx_s[t] = besti;
        out[IDX_OFF + n0 + t] = (float)besti;
        dist = zn_s[t] + bestv;
    }
    if (t < 64) {
        #pragma unroll
        for (int off = 32; off > 0; off >>= 1) dist += __shfl_down(dist, off, 64);
        if (t == 0) part[blockIdx.x] = dist;
    }
    __syncthreads();
    {
        int r = t & 63, dq = t >> 6;
        int idx = fidx_s[r];
        const float4* wrow = reinterpret_cast<const float4*>(w + (size_t)idx * DDIM + dq * 64);
        float* obase = out + ((size_t)bb * DDIM + dq * 64) * 1024 + rem0 + r;
        #pragma unroll
        for (int d4 = 0; d4 < 16; ++d4) {
            float4 v = wrow[d4];
            obase[(size_t)(d4 * 4 + 0) * 1024] = v.x;
            obase[(size_t)(d4 * 4 + 1) * 1024] = v.y;
            obase[(size_t)(d4 * 4 + 2) * 1024] = v.z;
            obase[(size_t)(d4 * 4 + 3) * 1024] = v.w;
        }
    }
}

extern "C" void kernel_launch(void* const* d_in, const int* in_sizes, int n_in,
                              void* d_out, int out_size, void* d_ws, size_t ws_size,
                              hipStream_t stream) {
    const float* z = (const float*)d_in[0];
    const float* w = (const float*)d_in[1];
    float* out = (float*)d_out;
    if (ws_size >= WS_NEED) {
        unsigned char* ws = (unsigned char*)d_ws;
        float* part = (float*)(ws + WS_PART);
        vq_prep<<<1024, 256, 0, stream>>>(w, ws);
        vq_stage1<<<512, 256, 0, stream>>>(z, ws);
        vq_flagmerge<<<64, 256, 0, stream>>>(ws);
        vq_rescore3<<<1024, 256, 0, stream>>>(z, w, ws);
        vq_gather<<<256, 256, 0, stream>>>(z, w, ws, out, part);
        vq_finish_kernel<<<1, 256, 0, stream>>>(part, out);
    } else {
        float* part = (float*)d_ws;
        vq_main_fp32<<<NROWS / fb::BM, 256, 0, stream>>>(z, w, out, part);
        vq_finish_kernel<<<1, 256, 0, stream>>>(part, out);
    }
}

// Round 13
// 148.473 us; speedup vs baseline: 1.3927x; 1.1137x over previous
//
#include <hip/hip_runtime.h>
#include <math.h>

typedef _Float16 half8 __attribute__((ext_vector_type(8)));
typedef float f32x4 __attribute__((ext_vector_type(4)));

namespace {
constexpr int NROWS = 16384;        // 16*32*32
constexpr int DDIM  = 256;
constexpr int KCODES = 8192;
constexpr size_t LOSS_OFF = (size_t)16 * 256 * 32 * 32;  // 4194304
constexpr size_t IDX_OFF  = LOSS_OFF + 1;
constexpr float LSCALE = 2048.f;
constexpr float LINV   = 1.f / 2048.f;
// workspace layout (bytes)
constexpr size_t WS_WH   = 0;                    // 4 MB fp16 hi plane, swizzled
constexpr size_t WS_WN   = 4194304;              // 8192 f32 |w|^2
constexpr size_t WS_PV   = WS_WN + 32768;        // [2][16384] f32 best value per half
constexpr size_t WS_PI   = WS_PV + 131072;       // [2][16384] i32 best idx per half
constexpr size_t WS_PS2  = WS_PI + 131072;       // [2][16384] f32 2nd-best per half
constexpr size_t WS_THA  = WS_PS2 + 131072;      // 16384 f32 per-row |zh|
constexpr size_t WS_THB  = WS_THA + 65536;       // 16384 f32 per-row |z-zh|
constexpr size_t WS_IDX  = WS_THB + 65536;       // 16384 i32 preliminary indices
constexpr size_t WS_FLG  = WS_IDX + 65536;       // 16384 i32 flagged? (0/1)
constexpr size_t WS_LIST = WS_FLG + 65536;       // 16384 i32 flagged-row list
constexpr size_t WS_RSV  = WS_LIST + 65536;      // [16384][16] f32 rescore slice vals
constexpr size_t WS_RSI  = WS_RSV + 1048576;     // [16384][16] i32 rescore slice idx
constexpr size_t WS_CNT  = WS_RSI + 1048576;     // u32 flagged count
constexpr size_t WS_PART = WS_CNT + 256;         // 512 f32 loss partials
constexpr size_t WS_BMAX = WS_PART + 2048;       // [1024][2] f32 per-block maxima
constexpr size_t WS_NEED = WS_BMAX + 8192;       // ~7.1 MB (< 8.7 MB proven in r3)
}

// ============================================================================
// Pre-convert codebook: fp32 -> fp16 hi plane (swizzled); |w|^2 per code;
// per-block maxima via plain stores (r6: same-address atomicMax cost ~130us).
// Block 0 zeroes the flag counter (r10-validated pattern).
// Plane: [tile=code>>7][kc=d>>6][c=code&127][g^(c&7)] x 16B
// ============================================================================
__global__ __launch_bounds__(256)
void vq_prep(const float* __restrict__ w, unsigned char* __restrict__ ws)
{
    __shared__ float rF[4], rS[4];
    if (blockIdx.x == 0 && threadIdx.x == 0) *(unsigned*)(ws + WS_CNT) = 0u;
    const int tau = blockIdx.x * 256 + threadIdx.x;   // 0..262143
    const int gcode = tau >> 5;                       // 0..8191
    const int sub = tau & 31;
    const int kc = sub >> 3, g = sub & 7;
    const float* src = w + (size_t)gcode * 256 + kc * 64 + g * 8;
    float x[8];
    *reinterpret_cast<float4*>(x)     = *reinterpret_cast<const float4*>(src);
    *reinterpret_cast<float4*>(x + 4) = *reinterpret_cast<const float4*>(src + 4);
    half8 hi;
    float sq = 0.f, fq = 0.f;
    #pragma unroll
    for (int j = 0; j < 8; ++j) {
        float v = x[j];
        sq = fmaf(v, v, sq);
        _Float16 h = (_Float16)v;
        hi[j] = h;
        float res = v - (float)h;
        fq = fmaf(res, res, fq);
    }
    const size_t off = (size_t)(gcode >> 7) * 65536 + (size_t)kc * 16384
                     + (size_t)(gcode & 127) * 128 + (size_t)((g ^ (gcode & 7)) << 4);
    *reinterpret_cast<half8*>(ws + WS_WH + off) = hi;
    #pragma unroll
    for (int o = 16; o > 0; o >>= 1) {
        sq += __shfl_down(sq, o, 32);
        fq += __shfl_down(fq, o, 32);
    }
    if (sub == 0) ((float*)(ws + WS_WN))[gcode] = sq;
    float sqc = (sub == 0) ? sq : 0.f;
    float fqc = (sub == 0) ? fq : 0.f;
    #pragma unroll
    for (int o = 32; o > 0; o >>= 1) {
        sqc = fmaxf(sqc, __shfl_xor(sqc, o, 64));
        fqc = fmaxf(fqc, __shfl_xor(fqc, o, 64));
    }
    if ((threadIdx.x & 63) == 0) { rF[threadIdx.x >> 6] = fqc; rS[threadIdx.x >> 6] = sqc; }
    __syncthreads();
    if (threadIdx.x == 0) {
        float* bm = (float*)(ws + WS_BMAX);
        bm[blockIdx.x * 2]     = fmaxf(fmaxf(rF[0], rF[1]), fmaxf(rF[2], rF[3]));
        bm[blockIdx.x * 2 + 1] = fmaxf(fmaxf(rS[0], rS[1]), fmaxf(rS[2], rS[3]));
    }
}

// ============================================================================
// Stage 1 -- FROZEN r9/r11/r12 config (98 us, MfmaUtil 30, VGPR 104, WRITE
// ~0.45MB). Do NOT touch: launch_bounds(256,2) [r8/r10: tighter bounds spill
// ah[] -> 13-64MB scratch]; no setprio [r7: 98->111].
// Block = 256 thr (4 waves, 2M x 2N), 64 rows x 4096 codes (half).
// grid 512: rg = bid>>1, half = bid&1. 4x16KB arena, vmcnt 8/4/0.
// ============================================================================
__global__ __launch_bounds__(256, 2)
void vq_stage1(const float* __restrict__ z, unsigned char* __restrict__ ws)
{
    __shared__ __align__(16) unsigned char A[65536];
    __shared__ float MS1[64][2];
    __shared__ int   MI1[64][2];
    __shared__ float MS2[64][2];
    __shared__ float STE[64][4];
    __shared__ float STN[64][4];

    const int t = threadIdx.x;
    const int lane = t & 63;
    const int wv = t >> 6;          // 0..3
    const int wm = wv >> 1;         // row group of 32
    const int wng = wv & 1;         // code group of 64
    const int rl = lane & 15, lh = lane >> 4;
    const int bid = blockIdx.x;
    const int rg = bid >> 1;
    const int half = bid & 1;
    const int r0 = rg * 64;
    const int bb = r0 >> 10;
    const int rem0 = r0 & 1023;
    const float* zbase = z + (size_t)bb * 256 * 1024 + rem0;

    // ---- stage zh (fp16, swizzled) + per-row residual/norm partials ----
    {
        const int r = t & 63;
        const int ob = t >> 6;               // 0..3 -> d range [ob*64, ob*64+64)
        float e2 = 0.f, n2 = 0.f;
        #pragma unroll
        for (int i = 0; i < 8; ++i) {
            const int o = ob * 8 + i;        // k-octet
            half8 hi;
            #pragma unroll
            for (int j = 0; j < 8; ++j) {
                float v = zbase[(size_t)(o * 8 + j) * 1024 + r];
                _Float16 h = (_Float16)v;
                hi[j] = h;
                float res = v - (float)h;
                e2 = fmaf(res, res, e2);
                n2 = fmaf((float)h, (float)h, n2);
            }
            *reinterpret_cast<half8*>(A + r * 512 + ((o ^ (r & 7)) << 4)) = hi;
        }
        STE[r][ob] = e2;
        STN[r][ob] = n2;
    }
    __syncthreads();

    // ---- per-row norm components (written once, by half==0 blocks) ----
    if (t < 64 && half == 0) {
        float e2 = STE[t][0] + STE[t][1] + STE[t][2] + STE[t][3];
        float n2 = STN[t][0] + STN[t][1] + STN[t][2] + STN[t][3];
        ((float*)(ws + WS_THA))[r0 + t] = sqrtf(n2);
        ((float*)(ws + WS_THB))[r0 + t] = sqrtf(e2);
    }

    // ---- hoist zh fragments to registers: ah[kc][ks][m] ----
    half8 ah[4][2][2];
    #pragma unroll
    for (int kc = 0; kc < 4; ++kc)
        #pragma unroll
        for (int ks = 0; ks < 2; ++ks)
            #pragma unroll
            for (int m = 0; m < 2; ++m) {
                const int r = wm * 32 + m * 16 + rl;
                const int g = kc * 8 + ks * 4 + lh;
                ah[kc][ks][m] = *reinterpret_cast<const half8*>(
                    A + r * 512 + ((g ^ (r & 7)) << 4));
            }
    __syncthreads();    // staging region now free -> W-chunk arena

    const unsigned char* wplane = ws + WS_WH;
    auto issue = [&](int ct) {
        const int kcs = ct & 3;
        const int gtile = half * 32 + (ct >> 2);
        const unsigned char* src = wplane + (size_t)gtile * 65536 + (size_t)kcs * 16384;
        unsigned char* dst = A + kcs * 16384;
        #pragma unroll
        for (int i = 0; i < 4; ++i) {
            const int gran = wv * 256 + i * 64 + lane;
            __builtin_amdgcn_global_load_lds(
                (const __attribute__((address_space(1))) unsigned int*)(src + (size_t)gran * 16),
                (__attribute__((address_space(3))) unsigned int*)(dst + (size_t)gran * 16), 16, 0, 0);
        }
    };
    issue(0); issue(1); issue(2);

    float s1v[8], s2v[8];
    int   i1v[8];
    #pragma unroll
    for (int s = 0; s < 8; ++s) { s1v[s] = INFINITY; s2v[s] = INFINITY; i1v[s] = 0; }
    const float* wnp = (const float*)(ws + WS_WN);

    f32x4 acc[2][4];
    for (int t4 = 0; t4 < 32; ++t4) {
        #pragma unroll
        for (int kc = 0; kc < 4; ++kc) {
            const int ct = t4 * 4 + kc;     // chunk index 0..127, slot == kc
            if (t4 == 31) {
                if (kc == 2)      asm volatile("s_waitcnt vmcnt(4)" ::: "memory");
                else if (kc == 3) asm volatile("s_waitcnt vmcnt(0)" ::: "memory");
                else              asm volatile("s_waitcnt vmcnt(8)" ::: "memory");
            } else {
                asm volatile("s_waitcnt vmcnt(8)" ::: "memory");
            }
            __builtin_amdgcn_s_barrier();
            asm volatile("" ::: "memory");
            if (ct + 3 < 128) issue(ct + 3);

            if (kc == 0) {
                #pragma unroll
                for (int m = 0; m < 2; ++m)
                    #pragma unroll
                    for (int n = 0; n < 4; ++n) acc[m][n] = (f32x4)0.f;
            }
            const unsigned char* wb = A + kc * 16384;
            #pragma unroll
            for (int ks = 0; ks < 2; ++ks) {
                half8 bf[4];
                #pragma unroll
                for (int n = 0; n < 4; ++n) {
                    const int cc = wng * 64 + n * 16 + rl;
                    const int gg = ks * 4 + lh;
                    bf[n] = *reinterpret_cast<const half8*>(
                        wb + cc * 128 + ((gg ^ (cc & 7)) << 4));
                }
                #pragma unroll
                for (int m = 0; m < 2; ++m)
                    #pragma unroll
                    for (int n = 0; n < 4; ++n)
                        acc[m][n] = __builtin_amdgcn_mfma_f32_16x16x32_f16(
                            ah[kc][ks][m], bf[n], acc[m][n], 0, 0, 0);
            }
            if (kc == 3) {
                // tile epilogue: s = |w|^2 - 2*dot ; top-2 update (codes ascending)
                const int codebase = half * 4096 + t4 * 128 + wng * 64;
                #pragma unroll
                for (int n = 0; n < 4; ++n) {
                    const int code = codebase + n * 16 + rl;
                    const float wnv = wnp[code];
                    #pragma unroll
                    for (int m = 0; m < 2; ++m)
                        #pragma unroll
                        for (int rr = 0; rr < 4; ++rr) {
                            const int sl = m * 4 + rr;
                            float s = fmaf(-2.f, acc[m][n][rr], wnv);
                            bool lt = s < s1v[sl];
                            s2v[sl] = fminf(s2v[sl], fmaxf(s, s1v[sl]));
                            i1v[sl] = lt ? code : i1v[sl];
                            s1v[sl] = fminf(s1v[sl], s);
                        }
                }
            }
        }
    }

    // ---- cross-lane top-2 merge (16 lanes sharing a row) ----
    #pragma unroll
    for (int sl = 0; sl < 8; ++sl) {
        float v1 = s1v[sl], v2 = s2v[sl];
        int ii = i1v[sl];
        #pragma unroll
        for (int o = 8; o > 0; o >>= 1) {
            float ov1 = __shfl_xor(v1, o, 16);
            float ov2 = __shfl_xor(v2, o, 16);
            int   oi  = __shfl_xor(ii, o, 16);
            float ns2 = fminf(fmaxf(v1, ov1), fminf(v2, ov2));
            bool tk = (ov1 < v1) || (ov1 == v1 && oi < ii);
            v1 = tk ? ov1 : v1;
            ii = tk ? oi : ii;
            v2 = ns2;
        }
        if (rl == 0) {
            const int m = sl >> 2, rr = sl & 3;
            const int row = wm * 32 + m * 16 + lh * 4 + rr;
            MS1[row][wng] = v1; MI1[row][wng] = ii; MS2[row][wng] = v2;
        }
    }
    __syncthreads();
    if (t < 64) {
        float v0 = MS1[t][0], v1 = MS1[t][1];
        int   i0 = MI1[t][0], i1b = MI1[t][1];
        float s20 = MS2[t][0], s21 = MS2[t][1];
        bool tk = (v1 < v0) || (v1 == v0 && i1b < i0);
        float bs1 = tk ? v1 : v0;
        int bi = tk ? i1b : i0;
        float bs2 = fminf(fmaxf(v0, v1), fminf(s20, s21));
        const int grow = r0 + t;
        ((float*)(ws + WS_PV))[half * 16384 + grow] = bs1;
        ((int*)(ws + WS_PI))[half * 16384 + grow] = bi;
        ((float*)(ws + WS_PS2))[half * 16384 + grow] = bs2;
    }
}

// ============================================================================
// Merge halves -> preliminary idx; flag rows (gap < TH) -> FLG array + list.
// Absorbs maxreduce: redundant 2KB BMAX reduce (bitwise-identical Fm/Wm).
// ============================================================================
__global__ __launch_bounds__(256)
void vq_flagmerge(unsigned char* __restrict__ ws)
{
    __shared__ float sF[4], sS[4];
    const int t = threadIdx.x;
    const float* bm = (const float*)(ws + WS_BMAX);
    float f = 0.f, s = 0.f;
    #pragma unroll
    for (int i = 0; i < 4; ++i) {
        f = fmaxf(f, bm[(t + i * 256) * 2]);
        s = fmaxf(s, bm[(t + i * 256) * 2 + 1]);
    }
    #pragma unroll
    for (int o = 32; o > 0; o >>= 1) {
        f = fmaxf(f, __shfl_xor(f, o, 64));
        s = fmaxf(s, __shfl_xor(s, o, 64));
    }
    if ((t & 63) == 0) { sF[t >> 6] = f; sS[t >> 6] = s; }
    __syncthreads();
    const float Fm = sqrtf(fmaxf(fmaxf(sF[0], sF[1]), fmaxf(sF[2], sF[3])));
    const float Wm = sqrtf(fmaxf(fmaxf(sS[0], sS[1]), fmaxf(sS[2], sS[3])));

    const int row = blockIdx.x * 256 + t;
    const float* PV  = (const float*)(ws + WS_PV);
    const int*   PI  = (const int*)(ws + WS_PI);
    const float* PS2 = (const float*)(ws + WS_PS2);
    float v0 = PV[row], v1 = PV[16384 + row];
    int   i0 = PI[row], i1 = PI[16384 + row];
    float s20 = PS2[row], s21 = PS2[16384 + row];
    bool tk = (v1 < v0) || (v1 == v0 && i1 < i0);
    float bs1 = tk ? v1 : v0;
    int bi = tk ? i1 : i0;
    float bs2 = fminf(fmaxf(v0, v1), fminf(s20, s21));
    ((int*)(ws + WS_IDX))[row] = bi;
    float th = 0.75f * (((const float*)(ws + WS_THA))[row] * Fm
                      + ((const float*)(ws + WS_THB))[row] * Wm) + 0.03f;
    int fl = (bs2 - bs1 < th) ? 1 : 0;
    ((int*)(ws + WS_FLG))[row] = fl;
    if (fl) {
        unsigned p = atomicAdd((unsigned*)(ws + WS_CNT), 1u);
        ((int*)(ws + WS_LIST))[p] = row;
    }
}

// ============================================================================
// Exact-class 3-pass MFMA rescore of flagged rows, SLICED over codes.
// Item = (group of 64 flagged rows, slice of 512 codes) -- 16 slices (was 8):
// halves per-item compute, doubles item parallelism -> wall ~halved.
// dot = zh*wh + (zl*wh + zh*wl)/2048. Partials keyed by ROW -> deterministic.
// ============================================================================
__global__ __launch_bounds__(256, 1)
void vq_rescore3(const float* __restrict__ z, const float* __restrict__ w,
                 unsigned char* __restrict__ ws)
{
    // LDS: [0,32K) zh | [32K,64K) zl | [64K,128K) arena 2 slots x (wh16K+wl16K) | merge
    __shared__ __align__(16) unsigned char L[132352];
    float* MS1 = (float*)(L + 131072);           // [64][2]
    int*   MI1 = (int*)(L + 131072 + 512);       // [64][2]
    int*   rowsS = (int*)(L + 131072 + 1024);    // [64]

    const int t = threadIdx.x;
    const int lane = t & 63;
    const int wv = t >> 6;
    const int wm = wv >> 1, wng = wv & 1;
    const int rl = lane & 15, lh = lane >> 4;
    const unsigned cnt = *(const unsigned*)(ws + WS_CNT);
    if (cnt == 0) return;
    const unsigned ngroups = (cnt + 63u) >> 6;
    const unsigned items = ngroups * 16u;
    const int* list = (const int*)(ws + WS_LIST);
    const float* wnp = (const float*)(ws + WS_WN);
    float* RSV = (float*)(ws + WS_RSV);
    int*   RSI = (int*)(ws + WS_RSI);

    // stage one W chunk (128 codes x 64 d, fp32 -> hi/lo fp16) into arena slot
    auto stageW = [&](int cb, int kc, int slot) {
        unsigned char* whb = L + 65536 + slot * 32768;
        unsigned char* wlb = whb + 16384;
        #pragma unroll
        for (int i = 0; i < 4; ++i) {
            int task = i * 256 + t;
            int c = task >> 3, go = task & 7;
            const float* wsrc = w + (size_t)(cb + c) * 256 + kc * 64 + go * 8;
            float x[8];
            *reinterpret_cast<float4*>(x)     = *reinterpret_cast<const float4*>(wsrc);
            *reinterpret_cast<float4*>(x + 4) = *reinterpret_cast<const float4*>(wsrc + 4);
            half8 hi, lo;
            #pragma unroll
            for (int j = 0; j < 8; ++j) {
                float v = x[j];
                _Float16 h = (_Float16)v;
                hi[j] = h;
                lo[j] = (_Float16)((v - (float)h) * LSCALE);
            }
            const int woff = c * 128 + ((go ^ (c & 7)) << 4);
            *reinterpret_cast<half8*>(whb + woff) = hi;
            *reinterpret_cast<half8*>(wlb + woff) = lo;
        }
    };

    for (unsigned item = blockIdx.x; item < items; item += gridDim.x) {
        const unsigned g = item >> 4;
        const int s = (int)(item & 15u);

        if (t < 64) {
            unsigned li = g * 64u + (unsigned)t;
            rowsS[t] = list[li < cnt ? li : cnt - 1u];
        }
        __syncthreads();

        // ---- stage gathered z rows -> zh/zl (fp16, swizzled) ----
        {
            const int r = t & 63, qq = t >> 6;
            const int row = rowsS[r];
            const float* zb = z + ((size_t)(row >> 10) * 256 + qq * 64) * 1024 + (row & 1023);
            #pragma unroll
            for (int o = 0; o < 8; ++o) {
                half8 hi, lo;
                #pragma unroll
                for (int j = 0; j < 8; ++j) {
                    float v = zb[(size_t)(o * 8 + j) * 1024];
                    _Float16 h = (_Float16)v;
                    hi[j] = h;
                    lo[j] = (_Float16)((v - (float)h) * LSCALE);
                }
                const int go = qq * 8 + o;
                const int zoff = r * 512 + ((go ^ (r & 7)) << 4);
                *reinterpret_cast<half8*>(L + zoff) = hi;
                *reinterpret_cast<half8*>(L + 32768 + zoff) = lo;
            }
        }
        __syncthreads();

        // ---- hoist zh fragments ----
        half8 ah[4][2][2];
        #pragma unroll
        for (int kc = 0; kc < 4; ++kc)
            #pragma unroll
            for (int ks = 0; ks < 2; ++ks)
                #pragma unroll
                for (int m = 0; m < 2; ++m) {
                    const int r = wm * 32 + m * 16 + rl;
                    const int gg = kc * 8 + ks * 4 + lh;
                    ah[kc][ks][m] = *reinterpret_cast<const half8*>(
                        L + r * 512 + ((gg ^ (r & 7)) << 4));
                }

        float bv[8]; int bix[8];
        #pragma unroll
        for (int sl = 0; sl < 8; ++sl) { bv[sl] = INFINITY; bix[sl] = 0; }

        const int cbase0 = s * 512;
        stageW(cbase0, 0, 0);
        __syncthreads();

        f32x4 accM[2][4], accC[2][4];
        for (int tile = 0; tile < 4; ++tile) {
            const int cb = cbase0 + tile * 128;
            #pragma unroll
            for (int kc = 0; kc < 4; ++kc) {
                // prefetch next chunk into the other slot (overlaps with MFMA)
                if (kc < 3)           stageW(cb, kc + 1, (kc + 1) & 1);
                else if (tile < 3)    stageW(cbase0 + (tile + 1) * 128, 0, 0);

                if (kc == 0) {
                    #pragma unroll
                    for (int m = 0; m < 2; ++m)
                        #pragma unroll
                        for (int n = 0; n < 4; ++n) {
                            accM[m][n] = (f32x4)0.f;
                            accC[m][n] = (f32x4)0.f;
                        }
                }
                const unsigned char* whb = L + 65536 + (kc & 1) * 32768;
                const unsigned char* wlb = whb + 16384;
                #pragma unroll
                for (int ks = 0; ks < 2; ++ks) {
                    half8 bfh[4], bfl[4];
                    #pragma unroll
                    for (int n = 0; n < 4; ++n) {
                        const int cc = wng * 64 + n * 16 + rl;
                        const int gg = ks * 4 + lh;
                        const int woff = cc * 128 + ((gg ^ (cc & 7)) << 4);
                        bfh[n] = *reinterpret_cast<const half8*>(whb + woff);
                        bfl[n] = *reinterpret_cast<const half8*>(wlb + woff);
                    }
                    #pragma unroll
                    for (int m = 0; m < 2; ++m)
                        #pragma unroll
                        for (int n = 0; n < 4; ++n)
                            accM[m][n] = __builtin_amdgcn_mfma_f32_16x16x32_f16(
                                ah[kc][ks][m], bfh[n], accM[m][n], 0, 0, 0);
                    #pragma unroll
                    for (int m = 0; m < 2; ++m) {
                        const int r = wm * 32 + m * 16 + rl;
                        const int gg = kc * 8 + ks * 4 + lh;
                        half8 al = *reinterpret_cast<const half8*>(
                            L + 32768 + r * 512 + ((gg ^ (r & 7)) << 4));
                        #pragma unroll
                        for (int n = 0; n < 4; ++n)
                            accC[m][n] = __builtin_amdgcn_mfma_f32_16x16x32_f16(
                                al, bfh[n], accC[m][n], 0, 0, 0);
                    }
                    #pragma unroll
                    for (int m = 0; m < 2; ++m)
                        #pragma unroll
                        for (int n = 0; n < 4; ++n)
                            accC[m][n] = __builtin_amdgcn_mfma_f32_16x16x32_f16(
                                ah[kc][ks][m], bfl[n], accC[m][n], 0, 0, 0);
                }

                if (kc == 3) {
                    // tile epilogue: top-1 (codes ascending, strict <)
                    #pragma unroll
                    for (int n = 0; n < 4; ++n) {
                        const int code = cb + wng * 64 + n * 16 + rl;
                        const float wnv = wnp[code];
                        #pragma unroll
                        for (int m = 0; m < 2; ++m)
                            #pragma unroll
                            for (int rr = 0; rr < 4; ++rr) {
                                const int sl = m * 4 + rr;
                                float dot = accM[m][n][rr] + accC[m][n][rr] * LINV;
                                float sc = fmaf(-2.f, dot, wnv);
                                if (sc < bv[sl]) { bv[sl] = sc; bix[sl] = code; }
                            }
                    }
                }
                __syncthreads();   // chunk boundary: staged data ready / arena reusable
            }
        }

        // ---- cross-lane top-1 reduce + write row-keyed partials ----
        #pragma unroll
        for (int sl = 0; sl < 8; ++sl) {
            float v = bv[sl]; int ix = bix[sl];
            #pragma unroll
            for (int o = 8; o > 0; o >>= 1) {
                float ov = __shfl_xor(v, o, 16);
                int   oi = __shfl_xor(ix, o, 16);
                if (ov < v || (ov == v && oi < ix)) { v = ov; ix = oi; }
            }
            if (rl == 0) {
                const int row = wm * 32 + (sl >> 2) * 16 + lh * 4 + (sl & 3);
                MS1[row * 2 + wng] = v; MI1[row * 2 + wng] = ix;
            }
        }
        __syncthreads();
        if (t < 64) {
            float v0 = MS1[t * 2 + 0], v1 = MS1[t * 2 + 1];
            int   i0 = MI1[t * 2 + 0], i1 = MI1[t * 2 + 1];
            bool tk = (v1 < v0) || (v1 == v0 && i1 < i0);
            float v = tk ? v1 : v0;
            int ix = tk ? i1 : i0;
            if (g * 64u + (unsigned)t < cnt) {
                const int row = rowsS[t];
                RSV[(size_t)row * 16 + s] = v;
                RSI[(size_t)row * 16 + s] = ix;
            }
        }
        __syncthreads();   // before next item's staging
    }
}

// ============================================================================
// Final indices (inline 16-slice merge for flagged rows), gather z_q,
// direct loss partial sum. 512 blocks x 32 rows (2x TLP for the
// latency-bound scattered w-row reads; r12 had 256 blocks = 1/CU).
// ============================================================================
__global__ __launch_bounds__(256)
void vq_gather(const float* __restrict__ z, const float* __restrict__ w,
               const unsigned char* __restrict__ ws, float* __restrict__ out,
               float* __restrict__ part)
{
    __shared__ int sidx[32];
    __shared__ float s4[4];
    const int t = threadIdx.x;
    const int n0 = blockIdx.x * 32;
    const int bb = n0 >> 10, rem0 = n0 & 1023;
    if (t < 32) {
        const int row = n0 + t;
        int ix = ((const int*)(ws + WS_IDX))[row];
        if (((const int*)(ws + WS_FLG))[row]) {
            const float* RSV = (const float*)(ws + WS_RSV);
            const int*   RSI = (const int*)(ws + WS_RSI);
            float bvv = RSV[(size_t)row * 16];
            int bi = RSI[(size_t)row * 16];
            #pragma unroll
            for (int s = 1; s < 16; ++s) {
                float v = RSV[(size_t)row * 16 + s];
                int ix2 = RSI[(size_t)row * 16 + s];
                if (v < bvv || (v == bvv && ix2 < bi)) { bvv = v; bi = ix2; }
            }
            ix = bi;
        }
        sidx[t] = ix;
        out[IDX_OFF + row] = (float)ix;
    }
    __syncthreads();
    const int r = t & 31, dq = t >> 5;   // 8 d-groups of 32, lane = row
    const int idx = sidx[r];
    const float4* wrow = reinterpret_cast<const float4*>(w + (size_t)idx * 256 + dq * 32);
    const float* zb = z   + ((size_t)bb * 256 + dq * 32) * 1024 + rem0 + r;
    float*       ob = out + ((size_t)bb * 256 + dq * 32) * 1024 + rem0 + r;
    float acc = 0.f;
    #pragma unroll
    for (int d4 = 0; d4 < 8; ++d4) {
        float4 v = wrow[d4];
        float z0 = zb[(size_t)(d4 * 4 + 0) * 1024];
        float z1 = zb[(size_t)(d4 * 4 + 1) * 1024];
        float z2 = zb[(size_t)(d4 * 4 + 2) * 1024];
        float z3 = zb[(size_t)(d4 * 4 + 3) * 1024];
        ob[(size_t)(d4 * 4 + 0) * 1024] = v.x;
        ob[(size_t)(d4 * 4 + 1) * 1024] = v.y;
        ob[(size_t)(d4 * 4 + 2) * 1024] = v.z;
        ob[(size_t)(d4 * 4 + 3) * 1024] = v.w;
        float d0 = z0 - v.x, d1 = z1 - v.y, d2 = z2 - v.z, d3 = z3 - v.w;
        acc = fmaf(d0, d0, acc); acc = fmaf(d1, d1, acc);
        acc = fmaf(d2, d2, acc); acc = fmaf(d3, d3, acc);
    }
    #pragma unroll
    for (int o = 32; o > 0; o >>= 1) acc += __shfl_down(acc, o, 64);
    if ((t & 63) == 0) s4[t >> 6] = acc;
    __syncthreads();
    if (t == 0) part[blockIdx.x] = s4[0] + s4[1] + s4[2] + s4[3];
}

__global__ void vq_finish_kernel(const float* __restrict__ part, float* __restrict__ out)
{
    __shared__ float s4[4];
    int t = threadIdx.x;
    float v = part[t] + part[t + 256];
    #pragma unroll
    for (int off = 32; off > 0; off >>= 1) v += __shfl_down(v, off, 64);
    if ((t & 63) == 0) s4[t >> 6] = v;
    __syncthreads();
    if (t == 0) {
        float tot = s4[0] + s4[1] + s4[2] + s4[3];
        out[LOSS_OFF] = 0.25f * tot / ((float)NROWS * (float)DDIM);
    }
}

// ============================================================================
// Fallback (proven round-2 fp32 path) used only when ws_size is too small.
// ============================================================================
namespace fb {
constexpr int BM = 64, BN = 64, NCHUNK = KCODES / BN, BSTR = 257;
}
__global__ __launch_bounds__(256, 1)
void vq_main_fp32(const float* __restrict__ z, const float* __restrict__ w,
                  float* __restrict__ out, float* __restrict__ part)
{
    using namespace fb;
    __shared__ float At[DDIM][BM];
    __shared__ float Bt[BN][BSTR];
    __shared__ float zn_s[BM];
    __shared__ float wn4[BM][5];
    __shared__ float cmin[BM][17];
    __shared__ int   cidx[BM][17];
    __shared__ int   fidx_s[BM];

    const int t = threadIdx.x;
    const int n0 = blockIdx.x * BM;
    const int bb = n0 >> 10;
    const int rem0 = n0 & 1023;
    const float* zbase = z + (size_t)bb * DDIM * 1024 + rem0;

    #pragma unroll
    for (int it = 0; it < 16; ++it) {
        int tau = t + it * 256;
        int d = tau >> 4;
        int r4 = (tau & 15) << 2;
        float4 v = *reinterpret_cast<const float4*>(zbase + (size_t)d * 1024 + r4);
        *reinterpret_cast<float4*>(&At[d][r4]) = v;
    }
    __syncthreads();
    if (t < BM) {
        float s = 0.f;
        #pragma unroll 8
        for (int d = 0; d < DDIM; ++d) { float v = At[d][t]; s = fmaf(v, v, s); }
        zn_s[t] = s;
    }
    const int ty = t >> 4, tx = t & 15;
    float rmin[4]; int ridx[4];
    #pragma unroll
    for (int i = 0; i < 4; ++i) { rmin[i] = INFINITY; ridx[i] = 0; }

    for (int nc = 0; nc < NCHUNK; ++nc) {
        const float* wb = w + (size_t)nc * BN * DDIM;
        #pragma unroll
        for (int it = 0; it < 16; ++it) {
            int tau = t + it * 256;
            int k = tau >> 6;
            int d4 = (tau & 63) << 2;
            float4 v = *reinterpret_cast<const float4*>(wb + (size_t)k * DDIM + d4);
            Bt[k][d4 + 0] = v.x; Bt[k][d4 + 1] = v.y;
            Bt[k][d4 + 2] = v.z; Bt[k][d4 + 3] = v.w;
        }
        __syncthreads();
        {
            int k = t & 63, q = t >> 6;
            float s = 0.f;
            const int d0 = q * 64;
            #pragma unroll 8
            for (int d = 0; d < 64; ++d) { float v = Bt[k][d0 + d]; s = fmaf(v, v, s); }
            wn4[k][q] = s;
        }
        float acc[4][4];
        #pragma unroll
        for (int i = 0; i < 4; ++i)
            #pragma unroll
            for (int j = 0; j < 4; ++j) acc[i][j] = 0.f;
        #pragma unroll 8
        for (int kk = 0; kk < DDIM; ++kk) {
            float a[4], bvv[4];
            *reinterpret_cast<float4*>(a) =
                *reinterpret_cast<const float4*>(&At[kk][ty << 2]);
            #pragma unroll
            for (int j = 0; j < 4; ++j) bvv[j] = Bt[(tx << 2) + j][kk];
            #pragma unroll
            for (int i = 0; i < 4; ++i)
                #pragma unroll
                for (int j = 0; j < 4; ++j) acc[i][j] = fmaf(a[i], bvv[j], acc[i][j]);
        }
        __syncthreads();
        #pragma unroll
        for (int j = 0; j < 4; ++j) {
            int c = (tx << 2) + j;
            float wn = wn4[c][0] + wn4[c][1] + wn4[c][2] + wn4[c][3];
            int gidx = nc * BN + c;
            #pragma unroll
            for (int i = 0; i < 4; ++i) {
                float s = fmaf(-2.f, acc[i][j], wn);
                if (s < rmin[i]) { rmin[i] = s; ridx[i] = gidx; }
            }
        }
    }
    #pragma unroll
    for (int i = 0; i < 4; ++i) {
        cmin[(ty << 2) + i][tx] = rmin[i];
        cidx[(ty << 2) + i][tx] = ridx[i];
    }
    __syncthreads();
    float dist = 0.f;
    if (t < BM) {
        float bestv = cmin[t][0]; int besti = cidx[t][0];
        #pragma unroll
        for (int x = 1; x < 16; ++x) {
            float v = cmin[t][x]; int ix = cidx[t][x];
            if (v < bestv || (v == bestv && ix < besti)) { bestv = v; besti = ix; }
        }
        fidx_s[t] = besti;
        out[IDX_OFF + n0 + t] = (float)besti;
        dist = zn_s[t] + bestv;
    }
    if (t < 64) {
        #pragma unroll
        for (int off = 32; off > 0; off >>= 1) dist += __shfl_down(dist, off, 64);
        if (t == 0) part[blockIdx.x] = dist;
    }
    __syncthreads();
    {
        int r = t & 63, dq = t >> 6;
        int idx = fidx_s[r];
        const float4* wrow = reinterpret_cast<const float4*>(w + (size_t)idx * DDIM + dq * 64);
        float* obase = out + ((size_t)bb * DDIM + dq * 64) * 1024 + rem0 + r;
        #pragma unroll
        for (int d4 = 0; d4 < 16; ++d4) {
            float4 v = wrow[d4];
            obase[(size_t)(d4 * 4 + 0) * 1024] = v.x;
            obase[(size_t)(d4 * 4 + 1) * 1024] = v.y;
            obase[(size_t)(d4 * 4 + 2) * 1024] = v.z;
            obase[(size_t)(d4 * 4 + 3) * 1024] = v.w;
        }
    }
}

__global__ void vq_finish_fb(const float* __restrict__ part, float* __restrict__ out)
{
    __shared__ float s4[4];
    int t = threadIdx.x;
    float v = part[t];
    #pragma unroll
    for (int off = 32; off > 0; off >>= 1) v += __shfl_down(v, off, 64);
    if ((t & 63) == 0) s4[t >> 6] = v;
    __syncthreads();
    if (t == 0) {
        float tot = s4[0] + s4[1] + s4[2] + s4[3];
        out[LOSS_OFF] = 0.25f * tot / ((float)NROWS * (float)DDIM);
    }
}

extern "C" void kernel_launch(void* const* d_in, const int* in_sizes, int n_in,
                              void* d_out, int out_size, void* d_ws, size_t ws_size,
                              hipStream_t stream) {
    const float* z = (const float*)d_in[0];
    const float* w = (const float*)d_in[1];
    float* out = (float*)d_out;
    if (ws_size >= WS_NEED) {
        unsigned char* ws = (unsigned char*)d_ws;
        float* part = (float*)(ws + WS_PART);
        vq_prep<<<1024, 256, 0, stream>>>(w, ws);
        vq_stage1<<<512, 256, 0, stream>>>(z, ws);
        vq_flagmerge<<<64, 256, 0, stream>>>(ws);
        vq_rescore3<<<1024, 256, 0, stream>>>(z, w, ws);
        vq_gather<<<512, 256, 0, stream>>>(z, w, ws, out, part);
        vq_finish_kernel<<<1, 256, 0, stream>>>(part, out);
    } else {
        float* part = (float*)d_ws;
        vq_main_fp32<<<NROWS / fb::BM, 256, 0, stream>>>(z, w, out, part);
        vq_finish_fb<<<1, 256, 0, stream>>>(part, out);
    }
}